// Round 9
// baseline (339.269 us; speedup 1.0000x reference)
//
#include <hip/hip_runtime.h>
#include <hip/hip_fp16.h>
#include <hip/hip_bf16.h>
#include <math.h>

typedef unsigned short u16;
typedef __attribute__((ext_vector_type(8))) short bf16x8;
typedef __attribute__((ext_vector_type(8))) unsigned short u16x8;
typedef __attribute__((ext_vector_type(4))) unsigned short u16x4;
typedef __attribute__((ext_vector_type(4))) float f32x4;

static constexpr float NEGF = -1e30f;
static constexpr float CLAMPF = 3.8918202981106265f; // -log(1/0.98 - 1)
static constexpr float SCALEF = 0.125f;              // 1/sqrt(64)
static constexpr float ASCALE = 16384.f;             // 2^14 alpha storage scale

__device__ __forceinline__ u16 f2bf(float x) {
    __hip_bfloat16 h = __float2bfloat16(x);
    return *reinterpret_cast<u16*>(&h);
}
__device__ __forceinline__ float bf2f(u16 b) {
    unsigned int u = ((unsigned int)b) << 16;
    return __uint_as_float(u);
}

// ---------------------------------------------------------------------------
// f32 -> bf16 conversion (vectorized 4/thread)
// ---------------------------------------------------------------------------
__global__ __launch_bounds__(256)
void cvt_f32_bf16_k(const float* __restrict__ src, u16* __restrict__ dst, int n4)
{
    int i = blockIdx.x * 256 + threadIdx.x;
    if (i < n4) {
        float4 v = ((const float4*)src)[i];
        u16x4 o; o.x = f2bf(v.x); o.y = f2bf(v.y); o.z = f2bf(v.z); o.w = f2bf(v.w);
        ((u16x4*)dst)[i] = o;
    }
}

// ---------------------------------------------------------------------------
// bf16 MFMA GEMM, NT form: C[m][n] = sum_k A[m][k]*B[n][k]  (+ epilogue)
// Tile TM x TN, BK=64, 256 threads = 4 waves in 2x2 grid, mfma_f32_16x16x32_bf16.
// EPI: 0=bf16(+opt bias), 1=fp16 sigmoid(CLAMP*tanh(x)) (fast rcp), 3=f32+bias,
//      4=bf16 V-transpose store (VT[(b*16+h)*64+d][k]) + bias
// ---------------------------------------------------------------------------
template<int TM, int TN, int EPI>
__global__ __launch_bounds__(256)
void mfma_nt(const u16* __restrict__ Ag, const u16* __restrict__ Bg,
             void* __restrict__ Cg, const float* __restrict__ bias,
             int K, int lda, int ldb, int ldc,
             long sAb, long sAh, long sBb, long sBh, long sCb, long sCh,
             int hdiv)
{
    __shared__ u16 As[TM * 64];
    __shared__ u16 Bs[TN * 64];

    int z = blockIdx.z;
    int b = z / hdiv, h = z % hdiv;
    const u16* A = Ag + (long)b * sAb + (long)h * sAh;
    const u16* B = Bg + (long)b * sBb + (long)h * sBh;

    int tid = threadIdx.x;
    int bm = blockIdx.y * TM, bn = blockIdx.x * TN;

    constexpr int AC = TM / 32;
    constexpr int BC = TN / 32;
    int srow = tid >> 3;          // 0..31
    int scol = (tid & 7) * 8;     // 0..56

    int wid = tid >> 6, lane = tid & 63;
    int wr = wid >> 1, wc = wid & 1;
    constexpr int MI = TM / 32;
    constexpr int NI = TN / 32;
    int arow0 = wr * (TM / 2) + (lane & 15);
    int bcol0 = wc * (TN / 2) + (lane & 15);
    int koff = (lane >> 4) * 8;

    f32x4 acc[MI][NI];
#pragma unroll
    for (int i = 0; i < MI; ++i)
#pragma unroll
        for (int j = 0; j < NI; ++j) acc[i][j] = (f32x4){0.f, 0.f, 0.f, 0.f};

    for (int kt = 0; kt < K; kt += 64) {
        u16x8 av[AC], bv[BC];
#pragma unroll
        for (int c = 0; c < AC; ++c)
            av[c] = *(const u16x8*)(A + (long)(bm + srow + 32 * c) * lda + kt + scol);
#pragma unroll
        for (int c = 0; c < BC; ++c)
            bv[c] = *(const u16x8*)(B + (long)(bn + srow + 32 * c) * ldb + kt + scol);
        __syncthreads();
#pragma unroll
        for (int c = 0; c < AC; ++c)
            *(u16x8*)&As[(srow + 32 * c) * 64 + scol] = av[c];
#pragma unroll
        for (int c = 0; c < BC; ++c)
            *(u16x8*)&Bs[(srow + 32 * c) * 64 + scol] = bv[c];
        __syncthreads();

#pragma unroll
        for (int ks = 0; ks < 2; ++ks) {
            bf16x8 af[MI], bfr[NI];
#pragma unroll
            for (int mi = 0; mi < MI; ++mi)
                af[mi] = *(const bf16x8*)&As[(arow0 + 16 * mi) * 64 + ks * 32 + koff];
#pragma unroll
            for (int ni = 0; ni < NI; ++ni)
                bfr[ni] = *(const bf16x8*)&Bs[(bcol0 + 16 * ni) * 64 + ks * 32 + koff];
#pragma unroll
            for (int mi = 0; mi < MI; ++mi)
#pragma unroll
                for (int ni = 0; ni < NI; ++ni)
                    acc[mi][ni] = __builtin_amdgcn_mfma_f32_16x16x32_bf16(
                        af[mi], bfr[ni], acc[mi][ni], 0, 0, 0);
        }
    }

    // Epilogue
    int rbase = bm + wr * (TM / 2) + (lane >> 4) * 4;
    int cbase = bn + wc * (TN / 2) + (lane & 15);
#pragma unroll
    for (int mi = 0; mi < MI; ++mi) {
#pragma unroll
        for (int ni = 0; ni < NI; ++ni) {
            int m0 = rbase + 16 * mi;
            int n = cbase + 16 * ni;
            if constexpr (EPI == 0) {
                u16* C = (u16*)Cg + (long)b * sCb + (long)h * sCh;
                float bvv = bias ? bias[n] : 0.f;
#pragma unroll
                for (int r = 0; r < 4; ++r)
                    C[(long)(m0 + r) * ldc + n] = f2bf(acc[mi][ni][r] + bvv);
            } else if constexpr (EPI == 1) {
                __half* C = (__half*)Cg + (long)b * sCb + (long)h * sCh;
#pragma unroll
                for (int r = 0; r < 4; ++r) {
                    float x = acc[mi][ni][r];
                    float e2 = __expf(2.f * x);
                    float tv = CLAMPF - (2.f * CLAMPF) * __builtin_amdgcn_rcpf(e2 + 1.f);
                    float pv = __builtin_amdgcn_rcpf(1.f + __expf(-tv));
                    C[(long)(m0 + r) * ldc + n] = __float2half(pv);
                }
            } else if constexpr (EPI == 3) {
                float* C = (float*)Cg + (long)b * sCb + (long)h * sCh;
                float bvv = bias[n];
#pragma unroll
                for (int r = 0; r < 4; ++r)
                    C[(long)(m0 + r) * ldc + n] = acc[mi][ni][r] + bvv;
            } else { // EPI == 4: VT[(b16h)*64 + d][k] = V[m=b*1024+k][n=h*64+d]
                u16* C = (u16*)Cg;
                float bvv = bias[n];
                long vaddr = ((long)((m0 >> 10) * 16 + (n >> 6)) * 64 + (n & 63)) * 1024
                             + (m0 & 1023);
                u16x4 pk;
                pk.x = f2bf(acc[mi][ni][0] + bvv);
                pk.y = f2bf(acc[mi][ni][1] + bvv);
                pk.z = f2bf(acc[mi][ni][2] + bvv);
                pk.w = f2bf(acc[mi][ni][3] + bvv);
                *(u16x4*)(C + vaddr) = pk;
            }
        }
    }
}

// ---------------------------------------------------------------------------
// Monotonic DP, LINEAR probability domain (scaled 2^14, mass-conserving).
// Wave-PIPELINED 4-way k-split: 4 waves per (b,h); wave w owns rows
// [256w,256(w+1)), lane owns 4 rows; wave w runs skewed 32 columns behind
// wave w-1. Boundary c3 values flow through a parity-double-buffered LDS
// ring written one phase ahead -> only ONE barrier per 32 columns.
// c[i] = a[i]*(1-p[i]) (from old state), a_new[i] = fmaf(a[i],p[i],c[i-1]).
// Depth-8 named-register global prefetch rolls across barriers (raw
// s_barrier + lgkmcnt only; vmcnt stays in flight).
// ---------------------------------------------------------------------------
static constexpr int DLT = 32;   // columns per phase

#define DPCL(J) (*(const uint2*)(p + (long)min(max((J), 0), 511) * 1024 + k0))

#define PSTEP(PC) do { \
    int jj = joff + it; \
    if (jj >= jbeg && jj < jend) { \
        float2 p01 = __half22float2(*(__half2*)&(PC).x); \
        float2 p23 = __half22float2(*(__half2*)&(PC).y); \
        float c0 = fmaf(-a0, p01.x, a0); \
        float c1 = fmaf(-a1, p01.y, a1); \
        float c2 = fmaf(-a2, p23.x, a2); \
        float c3 = fmaf(-a3, p23.y, a3); \
        float cp = __shfl_up(c3, 1, 64); \
        int slot = it & (DLT - 1); \
        if (lane == 63 && wave < 3) bnd[wave][par][slot] = c3; \
        if (lane == 0) cp = (wave == 0) ? 0.f : bnd[wave - 1][par ^ 1][slot]; \
        a0 = fmaf(a0, p01.x, cp); \
        a1 = fmaf(a1, p01.y, c0); \
        a2 = fmaf(a2, p23.x, c1); \
        a3 = fmaf(a3, p23.y, c2); \
        __half2 h01 = __floats2half2_rn(a0, a1), h23 = __floats2half2_rn(a2, a3); \
        uint2 st; st.x = *(unsigned*)&h01; st.y = *(unsigned*)&h23; \
        *(uint2*)(al + (long)(jj - q0) * 1024 + k0) = st; \
    } \
} while (0)

__global__ __launch_bounds__(256)
void mono_dp_k(const __half* __restrict__ P, __half* __restrict__ AL,
               float* __restrict__ STATE, int q0)
{
    int n = blockIdx.x;
    int tid = threadIdx.x;
    int wave = tid >> 6, lane = tid & 63;
    const __half* p = P + (long)n * 524288; // (512,1024) sigmoid probs
    __half* al = AL + (long)n * 262144;     // (256,1024) alpha chunk (scaled lin)
    float* stt = STATE + (long)n * 1024;
    int k0 = tid * 4;
    __shared__ float bnd[3][2][DLT];        // boundary ring: src wave, parity, slot

    float a0, a1, a2, a3;
    if (q0 == 0) {
        a0 = (tid == 0) ? ASCALE : 0.f; a1 = 0.f; a2 = 0.f; a3 = 0.f;
        __half2 h01 = __floats2half2_rn(a0, a1), h23 = __floats2half2_rn(a2, a3);
        uint2 st; st.x = *(unsigned*)&h01; st.y = *(unsigned*)&h23;
        *(uint2*)(al + k0) = st;   // alpha column 0 = init distribution
    } else {
        float4 s = *(const float4*)(stt + k0);
        a0 = s.x; a1 = s.y; a2 = s.z; a3 = s.w;
    }

    int jbeg = (q0 == 0) ? 1 : q0;
    int jend = q0 + 256;
    int ncols = jend - jbeg;                  // 255 or 256
    int nph = (ncols + DLT - 1) / DLT + 3;    // phases incl. 3-phase skew tail
    int joff = jbeg - wave * DLT;             // column of iteration 0 for this wave

    // rolling depth-8 prefetch; iteration it consumes p column (jj-1)
    uint2 f0 = DPCL(joff - 1);
    uint2 f1 = DPCL(joff + 0);
    uint2 f2 = DPCL(joff + 1);
    uint2 f3 = DPCL(joff + 2);
    uint2 f4 = DPCL(joff + 3);
    uint2 f5 = DPCL(joff + 4);
    uint2 f6 = DPCL(joff + 5);
    uint2 f7 = DPCL(joff + 6);

    int it = 0;
    for (int t = 0; t < nph; ++t) {
        int par = t & 1;
        for (int g = 0; g < DLT / 8; ++g) {
            PSTEP(f0); f0 = DPCL(joff + it + 7); ++it;
            PSTEP(f1); f1 = DPCL(joff + it + 7); ++it;
            PSTEP(f2); f2 = DPCL(joff + it + 7); ++it;
            PSTEP(f3); f3 = DPCL(joff + it + 7); ++it;
            PSTEP(f4); f4 = DPCL(joff + it + 7); ++it;
            PSTEP(f5); f5 = DPCL(joff + it + 7); ++it;
            PSTEP(f6); f6 = DPCL(joff + it + 7); ++it;
            PSTEP(f7); f7 = DPCL(joff + it + 7); ++it;
        }
        asm volatile("s_waitcnt lgkmcnt(0)" ::: "memory");
        __builtin_amdgcn_s_barrier();
        __builtin_amdgcn_sched_barrier(0);
    }

    float4 s; s.x = a0; s.y = a1; s.z = a2; s.w = a3;
    *(float4*)(stt + k0) = s;
}

// ---------------------------------------------------------------------------
// Fused attention, single-pass online softmax with 4-way k-split.
// grid (64 n, 16 q-groups); block = 4 waves; wave w handles 16 q x 256 k
// (k in [w*256,(w+1)*256)). Per 128-k tile: scores via MFMA (swapped: lane's
// l15 = q), tile-max, online rescale, w = alpha*exp(SCALE*(s-m)) -> swizzled
// wave-private LDS -> PV MFMA. Partials (m,l,o) combined across waves in LDS.
// ---------------------------------------------------------------------------
__global__ __launch_bounds__(256, 4)
void fused_attn_k(const u16* __restrict__ XQAQ, const u16* __restrict__ XK,
                  const u16* __restrict__ VT, const __half* __restrict__ AL,
                  u16* __restrict__ XO, int c0)
{
    __shared__ u16 wtile[4][2048];     // per-wave 16q x 128k bf16 (swizzled)
    __shared__ float co[4][16][64];    // per-wave partial O (q, d)
    __shared__ float cml[4][2][16];    // per-wave m, l per q

    int n = blockIdx.x; int b = n >> 4, h = n & 15;
    int tid = threadIdx.x, wave = tid >> 6, lane = tid & 63;
    int l15 = lane & 15, l4 = lane >> 4;
    int qc = blockIdx.y * 16;          // q base within chunk [0,256)
    int qg = c0 + qc;                  // q base within 512
    u16* wlds = wtile[wave];
    int swz = (l15 & 7) << 3;

    // Q B-frags (col=q=l15), hoisted
    const u16* qbase = XQAQ + (long)(b * 512 + qg + l15) * 2048 + 1024 + h * 64 + l4 * 8;
    bf16x8 qf0 = *(const bf16x8*)(qbase);
    bf16x8 qf1 = *(const bf16x8*)(qbase + 32);

    const u16* kbase = XK + (long)(b * 1024 + wave * 256 + l15) * 1024 + h * 64 + l4 * 8;
    const __half* abase = AL + (long)(n * 256 + qc + l15) * 1024 + wave * 256 + l4 * 4;
    const u16* vbase = VT + (long)(n * 64 + l15) * 1024 + wave * 256 + l4 * 8;

    float m = -3.0e38f, lsum = 0.f;
    f32x4 o[4];
#pragma unroll
    for (int df = 0; df < 4; ++df) o[df] = (f32x4){0.f, 0.f, 0.f, 0.f};

    for (int kt = 0; kt < 2; ++kt) {
        // alpha regs for this tile (q=l15, k = kt*128 + kf*16 + l4*4 + r)
        uint2 areg[8];
#pragma unroll
        for (int kf = 0; kf < 8; ++kf)
            areg[kf] = *(const uint2*)(abase + kt * 128 + kf * 16);

        // scores: s[kf][r] for q=l15, k = kt*128 + kf*16 + l4*4 + r
        f32x4 s[8];
#pragma unroll
        for (int kf = 0; kf < 8; ++kf) {
            const u16* kb = kbase + (long)(kt * 128 + kf * 16) * 1024;
            bf16x8 k0 = *(const bf16x8*)kb;
            bf16x8 k1 = *(const bf16x8*)(kb + 32);
            f32x4 acc = (f32x4){0.f, 0.f, 0.f, 0.f};
            acc = __builtin_amdgcn_mfma_f32_16x16x32_bf16(k0, qf0, acc, 0, 0, 0);
            acc = __builtin_amdgcn_mfma_f32_16x16x32_bf16(k1, qf1, acc, 0, 0, 0);
            s[kf] = acc;
        }

        // tile max per q (in-lane over 32 vals, then across l4 groups)
        float mt = -3.0e38f;
#pragma unroll
        for (int kf = 0; kf < 8; ++kf)
            mt = fmaxf(mt, fmaxf(fmaxf(s[kf][0], s[kf][1]), fmaxf(s[kf][2], s[kf][3])));
        mt = fmaxf(mt, __shfl_xor(mt, 16, 64));
        mt = fmaxf(mt, __shfl_xor(mt, 32, 64));

        float mn = fmaxf(m, mt);
        float f = __expf((m - mn) * SCALEF);
        m = mn;
        float negm = -mn * SCALEF;
        lsum *= f;
        // rescale o rows (q = l4*4 + r needs f from lane l4*4+r)
        float fr0 = __shfl(f, l4 * 4 + 0, 64);
        float fr1 = __shfl(f, l4 * 4 + 1, 64);
        float fr2 = __shfl(f, l4 * 4 + 2, 64);
        float fr3 = __shfl(f, l4 * 4 + 3, 64);
#pragma unroll
        for (int df = 0; df < 4; ++df) {
            o[df][0] *= fr0; o[df][1] *= fr1; o[df][2] *= fr2; o[df][3] *= fr3;
        }

        // w = alpha * exp(SCALE*(s - m)), accumulate l, store swizzled LDS
#pragma unroll
        for (int kf = 0; kf < 8; ++kf) {
            float2 a01 = __half22float2(*(__half2*)&areg[kf].x);
            float2 a23 = __half22float2(*(__half2*)&areg[kf].y);
            float w0 = a01.x * __expf(fmaf(s[kf][0], SCALEF, negm));
            float w1 = a01.y * __expf(fmaf(s[kf][1], SCALEF, negm));
            float w2 = a23.x * __expf(fmaf(s[kf][2], SCALEF, negm));
            float w3 = a23.y * __expf(fmaf(s[kf][3], SCALEF, negm));
            lsum += (w0 + w1) + (w2 + w3);
            u16x4 wp; wp.x = f2bf(w0); wp.y = f2bf(w1); wp.z = f2bf(w2); wp.w = f2bf(w3);
            *(u16x4*)&wlds[(l15 * 128 + kf * 16 + l4 * 4) ^ swz] = wp;
        }

        // PV over this 128-k tile
#pragma unroll
        for (int ks2 = 0; ks2 < 4; ++ks2) {
            bf16x8 wf = *(const bf16x8*)&wlds[(l15 * 128 + ks2 * 32 + l4 * 8) ^ swz];
#pragma unroll
            for (int df = 0; df < 4; ++df) {
                const u16* vb = vbase + (long)(df * 16) * 1024 + kt * 128 + ks2 * 32;
                bf16x8 vf = *(const bf16x8*)vb;
                o[df] = __builtin_amdgcn_mfma_f32_16x16x32_bf16(wf, vf, o[df], 0, 0, 0);
            }
        }
    }

    // finalize wave partial: full-row l (per q=l15)
    lsum += __shfl_xor(lsum, 16, 64);
    lsum += __shfl_xor(lsum, 32, 64);
    if (lane < 16) { cml[wave][0][l15] = m; cml[wave][1][l15] = lsum; }
#pragma unroll
    for (int df = 0; df < 4; ++df)
#pragma unroll
        for (int r = 0; r < 4; ++r)
            co[wave][l4 * 4 + r][df * 16 + l15] = o[df][r];
    __syncthreads();

    // combine 4 k-split partials; thread handles (q = tid>>4, d0 = (tid&15)*4)
    int q = tid >> 4, d0 = (tid & 15) * 4;
    float m0 = cml[0][0][q], m1 = cml[1][0][q], m2 = cml[2][0][q], m3 = cml[3][0][q];
    float ms = fmaxf(fmaxf(m0, m1), fmaxf(m2, m3));
    float c0w = __expf((m0 - ms) * SCALEF), c1w = __expf((m1 - ms) * SCALEF);
    float c2w = __expf((m2 - ms) * SCALEF), c3w = __expf((m3 - ms) * SCALEF);
    float lt = c0w * cml[0][1][q] + c1w * cml[1][1][q]
             + c2w * cml[2][1][q] + c3w * cml[3][1][q];
    f32x4 o0 = *(const f32x4*)&co[0][q][d0];
    f32x4 o1 = *(const f32x4*)&co[1][q][d0];
    f32x4 o2 = *(const f32x4*)&co[2][q][d0];
    f32x4 o3 = *(const f32x4*)&co[3][q][d0];
    float inv = __builtin_amdgcn_rcpf(lt);
    u16x4 st;
#pragma unroll
    for (int j = 0; j < 4; ++j)
        st[j] = f2bf((c0w * o0[j] + c1w * o1[j] + c2w * o2[j] + c3w * o3[j]) * inv);
    *(u16x4*)&XO[(long)(b * 512 + qg + q) * 1024 + h * 64 + d0] = st;
}

// ---------------------------------------------------------------------------
extern "C" void kernel_launch(void* const* d_in, const int* in_sizes, int n_in,
                              void* d_out, int out_size, void* d_ws, size_t ws_size,
                              hipStream_t stream)
{
    const float* q   = (const float*)d_in[0];
    const float* key = (const float*)d_in[1];
    const float* val = (const float*)d_in[2];
    const float* W   = (const float*)d_in[3];
    const float* ipb = (const float*)d_in[4];
    const float* ow  = (const float*)d_in[5];
    const float* ob  = (const float*)d_in[6];
    float* out = (float*)d_out;
    char* w = (char*)d_ws;

    // Workspace layout (bytes). Total 132,382,720 B (same as passing r3-r8).
    __half* PSIG   = (__half*)(w);                 // 64 MiB  (64,512,1024) fp16 sigmoid(phi)
    __half* ALPHAC = (__half*)(w + 67108864);      // 32 MiB  (64,256,1024) fp16 linear alpha
    float*  STATE  = (float*)(w + 100663296);      // 256 KiB (64,1024) f32
    u16*    XQAQ   = (u16*)(w + 100925440);        // 8 MiB   (2048,2048) bf16
    u16*    XK     = (u16*)(w + 109314048);        // 8 MiB   (4096,1024) bf16
    u16*    VT     = (u16*)(w + 117702656);        // 8 MiB   (64,64,1024) bf16
    u16*    XO     = (u16*)(w + 126091264);        // 4 MiB   (2048,1024) bf16
    u16*    OWBF   = (u16*)(w + 130285568);        // 2 MiB   (1024,1024) bf16
    // Overlays inside PSIG region (dead before phi GEMM writes):
    u16* QBF = (u16*)(w);                          // 4 MiB
    u16* KBF = (u16*)(w + 4194304);                // 8 MiB
    u16* VBF = (u16*)(w + 12582912);               // 8 MiB
    u16* WBF = (u16*)(w + 20971520);               // 8 MiB

    dim3 blk(256);

    // 0) f32 -> bf16 copies
    cvt_f32_bf16_k<<<dim3(2048), blk, 0, stream>>>(q, QBF, 524288);
    cvt_f32_bf16_k<<<dim3(4096), blk, 0, stream>>>(key, KBF, 1048576);
    cvt_f32_bf16_k<<<dim3(4096), blk, 0, stream>>>(val, VBF, 1048576);
    cvt_f32_bf16_k<<<dim3(4096), blk, 0, stream>>>(W, WBF, 1048576);
    cvt_f32_bf16_k<<<dim3(1024), blk, 0, stream>>>(ow, OWBF, 262144);

    // 1) XQAQ = q @ W[0:2048]^T + ipb[0:2048]  (cols 0..1023 = xqa, 1024.. = xq)
    mfma_nt<128, 128, 0><<<dim3(16, 16, 1), blk, 0, stream>>>(
        QBF, WBF, XQAQ, ipb, 1024, 1024, 1024, 2048, 0, 0, 0, 0, 0, 0, 1);
    // 2) XK = key @ W[2048:3072]^T + ipb[2048:3072]
    mfma_nt<128, 128, 0><<<dim3(8, 32, 1), blk, 0, stream>>>(
        KBF, WBF + 2097152, XK, ipb + 2048, 1024, 1024, 1024, 1024, 0, 0, 0, 0, 0, 0, 1);
    // 3) VT = transpose(val @ W[3072:4096]^T + ipb[3072:4096])
    mfma_nt<128, 128, 4><<<dim3(8, 32, 1), blk, 0, stream>>>(
        VBF, WBF + 3145728, VT, ipb + 3072, 1024, 1024, 1024, 0, 0, 0, 0, 0, 0, 0, 1);
    // 4) PSIG[n][q][k] = sigmoid(CLAMP * tanh(xqa_q . xk_k)) -> fp16
    mfma_nt<128, 128, 1><<<dim3(8, 4, 64), blk, 0, stream>>>(
        XQAQ, XK, PSIG, nullptr, 64, 2048, 1024, 1024,
        512L * 2048, 64, 1024L * 1024, 64, 8388608L, 524288L, 16);

    // 5) two 256-q chunks: DP -> fused attention (scores+softmax+PV)
    for (int c = 0; c < 2; ++c) {
        mono_dp_k<<<dim3(64), dim3(256), 0, stream>>>(PSIG, ALPHAC, STATE, c * 256);
        fused_attn_k<<<dim3(64, 16, 1), blk, 0, stream>>>(
            XQAQ, XK, VT, ALPHAC, XO, c * 256);
    }

    // 6) out = XO @ ow^T + ob  (f32)
    mfma_nt<128, 128, 3><<<dim3(8, 16, 1), blk, 0, stream>>>(
        XO, OWBF, out, ob, 1024, 1024, 1024, 1024, 0, 0, 0, 0, 0, 0, 1);
}

// Round 10
// 300.608 us; speedup vs baseline: 1.1286x; 1.1286x over previous
//
#include <hip/hip_runtime.h>
#include <hip/hip_fp16.h>
#include <hip/hip_bf16.h>
#include <math.h>

typedef unsigned short u16;
typedef __attribute__((ext_vector_type(8))) short bf16x8;
typedef __attribute__((ext_vector_type(8))) unsigned short u16x8;
typedef __attribute__((ext_vector_type(4))) unsigned short u16x4;
typedef __attribute__((ext_vector_type(4))) float f32x4;

static constexpr float NEGF = -1e30f;
static constexpr float CLAMPF = 3.8918202981106265f; // -log(1/0.98 - 1)
static constexpr float SCALEF = 0.125f;              // 1/sqrt(64)
static constexpr float ASCALE = 16384.f;             // 2^14 alpha storage scale

__device__ __forceinline__ u16 f2bf(float x) {
    __hip_bfloat16 h = __float2bfloat16(x);
    return *reinterpret_cast<u16*>(&h);
}
__device__ __forceinline__ float bf2f(u16 b) {
    unsigned int u = ((unsigned int)b) << 16;
    return __uint_as_float(u);
}

// ---------------------------------------------------------------------------
// f32 -> bf16 conversion (vectorized 4/thread)
// ---------------------------------------------------------------------------
__global__ __launch_bounds__(256)
void cvt_f32_bf16_k(const float* __restrict__ src, u16* __restrict__ dst, int n4)
{
    int i = blockIdx.x * 256 + threadIdx.x;
    if (i < n4) {
        float4 v = ((const float4*)src)[i];
        u16x4 o; o.x = f2bf(v.x); o.y = f2bf(v.y); o.z = f2bf(v.z); o.w = f2bf(v.w);
        ((u16x4*)dst)[i] = o;
    }
}

// ---------------------------------------------------------------------------
// bf16 MFMA GEMM, NT form: C[m][n] = sum_k A[m][k]*B[n][k]  (+ epilogue)
// Tile TM x TN, BK=64, 256 threads = 4 waves in 2x2 grid, mfma_f32_16x16x32_bf16.
// EPI: 0=bf16(+opt bias), 1=fp16 sigmoid(CLAMP*tanh(x)) (fast rcp), 3=f32+bias,
//      4=bf16 V-transpose store (VT[(b*16+h)*64+d][k]) + bias
// ---------------------------------------------------------------------------
template<int TM, int TN, int EPI>
__global__ __launch_bounds__(256)
void mfma_nt(const u16* __restrict__ Ag, const u16* __restrict__ Bg,
             void* __restrict__ Cg, const float* __restrict__ bias,
             int K, int lda, int ldb, int ldc,
             long sAb, long sAh, long sBb, long sBh, long sCb, long sCh,
             int hdiv)
{
    __shared__ u16 As[TM * 64];
    __shared__ u16 Bs[TN * 64];

    int z = blockIdx.z;
    int b = z / hdiv, h = z % hdiv;
    const u16* A = Ag + (long)b * sAb + (long)h * sAh;
    const u16* B = Bg + (long)b * sBb + (long)h * sBh;

    int tid = threadIdx.x;
    int bm = blockIdx.y * TM, bn = blockIdx.x * TN;

    constexpr int AC = TM / 32;
    constexpr int BC = TN / 32;
    int srow = tid >> 3;          // 0..31
    int scol = (tid & 7) * 8;     // 0..56

    int wid = tid >> 6, lane = tid & 63;
    int wr = wid >> 1, wc = wid & 1;
    constexpr int MI = TM / 32;
    constexpr int NI = TN / 32;
    int arow0 = wr * (TM / 2) + (lane & 15);
    int bcol0 = wc * (TN / 2) + (lane & 15);
    int koff = (lane >> 4) * 8;

    f32x4 acc[MI][NI];
#pragma unroll
    for (int i = 0; i < MI; ++i)
#pragma unroll
        for (int j = 0; j < NI; ++j) acc[i][j] = (f32x4){0.f, 0.f, 0.f, 0.f};

    for (int kt = 0; kt < K; kt += 64) {
        u16x8 av[AC], bv[BC];
#pragma unroll
        for (int c = 0; c < AC; ++c)
            av[c] = *(const u16x8*)(A + (long)(bm + srow + 32 * c) * lda + kt + scol);
#pragma unroll
        for (int c = 0; c < BC; ++c)
            bv[c] = *(const u16x8*)(B + (long)(bn + srow + 32 * c) * ldb + kt + scol);
        __syncthreads();
#pragma unroll
        for (int c = 0; c < AC; ++c)
            *(u16x8*)&As[(srow + 32 * c) * 64 + scol] = av[c];
#pragma unroll
        for (int c = 0; c < BC; ++c)
            *(u16x8*)&Bs[(srow + 32 * c) * 64 + scol] = bv[c];
        __syncthreads();

#pragma unroll
        for (int ks = 0; ks < 2; ++ks) {
            bf16x8 af[MI], bfr[NI];
#pragma unroll
            for (int mi = 0; mi < MI; ++mi)
                af[mi] = *(const bf16x8*)&As[(arow0 + 16 * mi) * 64 + ks * 32 + koff];
#pragma unroll
            for (int ni = 0; ni < NI; ++ni)
                bfr[ni] = *(const bf16x8*)&Bs[(bcol0 + 16 * ni) * 64 + ks * 32 + koff];
#pragma unroll
            for (int mi = 0; mi < MI; ++mi)
#pragma unroll
                for (int ni = 0; ni < NI; ++ni)
                    acc[mi][ni] = __builtin_amdgcn_mfma_f32_16x16x32_bf16(
                        af[mi], bfr[ni], acc[mi][ni], 0, 0, 0);
        }
    }

    // Epilogue
    int rbase = bm + wr * (TM / 2) + (lane >> 4) * 4;
    int cbase = bn + wc * (TN / 2) + (lane & 15);
#pragma unroll
    for (int mi = 0; mi < MI; ++mi) {
#pragma unroll
        for (int ni = 0; ni < NI; ++ni) {
            int m0 = rbase + 16 * mi;
            int n = cbase + 16 * ni;
            if constexpr (EPI == 0) {
                u16* C = (u16*)Cg + (long)b * sCb + (long)h * sCh;
                float bvv = bias ? bias[n] : 0.f;
#pragma unroll
                for (int r = 0; r < 4; ++r)
                    C[(long)(m0 + r) * ldc + n] = f2bf(acc[mi][ni][r] + bvv);
            } else if constexpr (EPI == 1) {
                __half* C = (__half*)Cg + (long)b * sCb + (long)h * sCh;
#pragma unroll
                for (int r = 0; r < 4; ++r) {
                    float x = acc[mi][ni][r];
                    float e2 = __expf(2.f * x);
                    float tv = CLAMPF - (2.f * CLAMPF) * __builtin_amdgcn_rcpf(e2 + 1.f);
                    float pv = __builtin_amdgcn_rcpf(1.f + __expf(-tv));
                    C[(long)(m0 + r) * ldc + n] = __float2half(pv);
                }
            } else if constexpr (EPI == 3) {
                float* C = (float*)Cg + (long)b * sCb + (long)h * sCh;
                float bvv = bias[n];
#pragma unroll
                for (int r = 0; r < 4; ++r)
                    C[(long)(m0 + r) * ldc + n] = acc[mi][ni][r] + bvv;
            } else { // EPI == 4: VT[(b16h)*64 + d][k] = V[m=b*1024+k][n=h*64+d]
                u16* C = (u16*)Cg;
                float bvv = bias[n];
                long vaddr = ((long)((m0 >> 10) * 16 + (n >> 6)) * 64 + (n & 63)) * 1024
                             + (m0 & 1023);
                u16x4 pk;
                pk.x = f2bf(acc[mi][ni][0] + bvv);
                pk.y = f2bf(acc[mi][ni][1] + bvv);
                pk.z = f2bf(acc[mi][ni][2] + bvv);
                pk.w = f2bf(acc[mi][ni][3] + bvv);
                *(u16x4*)(C + vaddr) = pk;
            }
        }
    }
}

// ---------------------------------------------------------------------------
// Monotonic DP, LINEAR probability domain (scaled 2^14, mass-conserving).
// Wave-PIPELINED 4-way k-split; wave w owns rows [256w,256(w+1)), lane owns
// 4 rows; wave w runs 32 columns behind wave w-1. Boundary c3 values flow
// through a parity-double-buffered LDS ring; at each phase start the 32
// boundary values are PRELOADED into static registers (8 broadcast
// ds_read_b128) so the LDS latency is off the per-column chain. Phases are
// specialized full/partial to keep guards out of the hot path. One barrier
// per 32 columns. c[i] = a[i]*(1-p[i]); a'[i] = fmaf(a[i],p[i],c[i-1]).
// ---------------------------------------------------------------------------
static constexpr int DLT = 32;   // columns per phase

#define DPCL(J) (*(const uint2*)(p + (long)min(max((J), 0), 511) * 1024 + k0))

#define PSTEPF(PC, BV) do { \
    int jj = joff + it; \
    float2 p01 = __half22float2(*(__half2*)&(PC).x); \
    float2 p23 = __half22float2(*(__half2*)&(PC).y); \
    float c0 = fmaf(-a0, p01.x, a0); \
    float c1 = fmaf(-a1, p01.y, a1); \
    float c2 = fmaf(-a2, p23.x, a2); \
    float c3 = fmaf(-a3, p23.y, a3); \
    float cp = __shfl_up(c3, 1, 64); \
    if (lane == 63) bnd[wave][par][it & (DLT - 1)] = c3; \
    if (lane == 0) cp = (wave == 0) ? 0.f : (BV); \
    a0 = fmaf(a0, p01.x, cp); \
    a1 = fmaf(a1, p01.y, c0); \
    a2 = fmaf(a2, p23.x, c1); \
    a3 = fmaf(a3, p23.y, c2); \
    __half2 h01 = __floats2half2_rn(a0, a1), h23 = __floats2half2_rn(a2, a3); \
    uint2 st; st.x = *(unsigned*)&h01; st.y = *(unsigned*)&h23; \
    *(uint2*)(al + (long)(jj - q0) * 1024 + k0) = st; \
    (PC) = DPCL(joff + it + 7); \
    ++it; \
} while (0)

#define PSTEPG(PC, BV) do { \
    int jj = joff + it; \
    if (jj >= jbeg && jj < jend) { \
        float2 p01 = __half22float2(*(__half2*)&(PC).x); \
        float2 p23 = __half22float2(*(__half2*)&(PC).y); \
        float c0 = fmaf(-a0, p01.x, a0); \
        float c1 = fmaf(-a1, p01.y, a1); \
        float c2 = fmaf(-a2, p23.x, a2); \
        float c3 = fmaf(-a3, p23.y, a3); \
        float cp = __shfl_up(c3, 1, 64); \
        if (lane == 63) bnd[wave][par][it & (DLT - 1)] = c3; \
        if (lane == 0) cp = (wave == 0) ? 0.f : (BV); \
        a0 = fmaf(a0, p01.x, cp); \
        a1 = fmaf(a1, p01.y, c0); \
        a2 = fmaf(a2, p23.x, c1); \
        a3 = fmaf(a3, p23.y, c2); \
        __half2 h01 = __floats2half2_rn(a0, a1), h23 = __floats2half2_rn(a2, a3); \
        uint2 st; st.x = *(unsigned*)&h01; st.y = *(unsigned*)&h23; \
        *(uint2*)(al + (long)(jj - q0) * 1024 + k0) = st; \
    } \
    (PC) = DPCL(joff + it + 7); \
    ++it; \
} while (0)

#define PH16(G, BX, BY) \
    G(f0, (BX).x); G(f1, (BX).y); G(f2, (BX).z); G(f3, (BX).w); \
    G(f4, (BY).x); G(f5, (BY).y); G(f6, (BY).z); G(f7, (BY).w);

__global__ __launch_bounds__(256)
void mono_dp_k(const __half* __restrict__ P, __half* __restrict__ AL,
               float* __restrict__ STATE, int q0)
{
    int n = blockIdx.x;
    int tid = threadIdx.x;
    int wave = tid >> 6, lane = tid & 63;
    const __half* p = P + (long)n * 524288; // (512,1024) sigmoid probs
    __half* al = AL + (long)n * 262144;     // (256,1024) alpha chunk (scaled lin)
    float* stt = STATE + (long)n * 1024;
    int k0 = tid * 4;
    __shared__ float bnd[4][2][DLT];        // boundary ring: src wave, parity, slot

    float a0, a1, a2, a3;
    if (q0 == 0) {
        a0 = (tid == 0) ? ASCALE : 0.f; a1 = 0.f; a2 = 0.f; a3 = 0.f;
        __half2 h01 = __floats2half2_rn(a0, a1), h23 = __floats2half2_rn(a2, a3);
        uint2 st; st.x = *(unsigned*)&h01; st.y = *(unsigned*)&h23;
        *(uint2*)(al + k0) = st;   // alpha column 0 = init distribution
    } else {
        float4 s = *(const float4*)(stt + k0);
        a0 = s.x; a1 = s.y; a2 = s.z; a3 = s.w;
    }

    int jbeg = (q0 == 0) ? 1 : q0;
    int jend = q0 + 256;
    int ncols = jend - jbeg;                  // 255 or 256
    int nph = (ncols + DLT - 1) / DLT + 3;    // phases incl. 3-phase skew
    int joff = jbeg - wave * DLT;             // column of iteration 0 for this wave

    // rolling depth-8 prefetch; iteration it consumes p column (jj-1)
    uint2 f0 = DPCL(joff - 1);
    uint2 f1 = DPCL(joff + 0);
    uint2 f2 = DPCL(joff + 1);
    uint2 f3 = DPCL(joff + 2);
    uint2 f4 = DPCL(joff + 3);
    uint2 f5 = DPCL(joff + 4);
    uint2 f6 = DPCL(joff + 5);
    uint2 f7 = DPCL(joff + 6);

    int it = 0;
    for (int t = 0; t < nph; ++t) {
        int par = t & 1;
        // preload this phase's 32 boundary values (written by wave-1 last phase)
        const float4* bsrc = (const float4*)&bnd[(wave + 3) & 3][par ^ 1][0];
        float4 bA = bsrc[0], bB = bsrc[1], bC = bsrc[2], bD = bsrc[3];
        float4 bE = bsrc[4], bF = bsrc[5], bG = bsrc[6], bH = bsrc[7];
        int j0ph = joff + it;
        if (j0ph >= jbeg && j0ph + DLT <= jend) {
            PH16(PSTEPF, bA, bB);
            PH16(PSTEPF, bC, bD);
            PH16(PSTEPF, bE, bF);
            PH16(PSTEPF, bG, bH);
        } else {
            PH16(PSTEPG, bA, bB);
            PH16(PSTEPG, bC, bD);
            PH16(PSTEPG, bE, bF);
            PH16(PSTEPG, bG, bH);
        }
        asm volatile("s_waitcnt lgkmcnt(0)" ::: "memory");
        __builtin_amdgcn_s_barrier();
        __builtin_amdgcn_sched_barrier(0);
    }

    float4 s; s.x = a0; s.y = a1; s.z = a2; s.w = a3;
    *(float4*)(stt + k0) = s;
}

// ---------------------------------------------------------------------------
// Fused attention, single-pass online softmax with 4-way k-split.
// grid (64 n, 16 q-groups); block = 4 waves; wave w handles 16 q x 256 k
// (k in [w*256,(w+1)*256)). Per 128-k tile: scores via MFMA (swapped: lane's
// l15 = q), tile-max, online rescale, w = alpha*exp(SCALE*(s-m)) -> swizzled
// wave-private LDS -> PV MFMA. Partials (m,l,o) combined across waves in LDS.
// ---------------------------------------------------------------------------
__global__ __launch_bounds__(256, 4)
void fused_attn_k(const u16* __restrict__ XQAQ, const u16* __restrict__ XK,
                  const u16* __restrict__ VT, const __half* __restrict__ AL,
                  u16* __restrict__ XO, int c0)
{
    __shared__ u16 wtile[4][2048];     // per-wave 16q x 128k bf16 (swizzled)
    __shared__ float co[4][16][64];    // per-wave partial O (q, d)
    __shared__ float cml[4][2][16];    // per-wave m, l per q

    int n = blockIdx.x; int b = n >> 4, h = n & 15;
    int tid = threadIdx.x, wave = tid >> 6, lane = tid & 63;
    int l15 = lane & 15, l4 = lane >> 4;
    int qc = blockIdx.y * 16;          // q base within chunk [0,256)
    int qg = c0 + qc;                  // q base within 512
    u16* wlds = wtile[wave];
    int swz = (l15 & 7) << 3;

    // Q B-frags (col=q=l15), hoisted
    const u16* qbase = XQAQ + (long)(b * 512 + qg + l15) * 2048 + 1024 + h * 64 + l4 * 8;
    bf16x8 qf0 = *(const bf16x8*)(qbase);
    bf16x8 qf1 = *(const bf16x8*)(qbase + 32);

    const u16* kbase = XK + (long)(b * 1024 + wave * 256 + l15) * 1024 + h * 64 + l4 * 8;
    const __half* abase = AL + (long)(n * 256 + qc + l15) * 1024 + wave * 256 + l4 * 4;
    const u16* vbase = VT + (long)(n * 64 + l15) * 1024 + wave * 256 + l4 * 8;

    float m = -3.0e38f, lsum = 0.f;
    f32x4 o[4];
#pragma unroll
    for (int df = 0; df < 4; ++df) o[df] = (f32x4){0.f, 0.f, 0.f, 0.f};

    for (int kt = 0; kt < 2; ++kt) {
        // alpha regs for this tile (q=l15, k = kt*128 + kf*16 + l4*4 + r)
        uint2 areg[8];
#pragma unroll
        for (int kf = 0; kf < 8; ++kf)
            areg[kf] = *(const uint2*)(abase + kt * 128 + kf * 16);

        // scores: s[kf][r] for q=l15, k = kt*128 + kf*16 + l4*4 + r
        f32x4 s[8];
#pragma unroll
        for (int kf = 0; kf < 8; ++kf) {
            const u16* kb = kbase + (long)(kt * 128 + kf * 16) * 1024;
            bf16x8 k0 = *(const bf16x8*)kb;
            bf16x8 k1 = *(const bf16x8*)(kb + 32);
            f32x4 acc = (f32x4){0.f, 0.f, 0.f, 0.f};
            acc = __builtin_amdgcn_mfma_f32_16x16x32_bf16(k0, qf0, acc, 0, 0, 0);
            acc = __builtin_amdgcn_mfma_f32_16x16x32_bf16(k1, qf1, acc, 0, 0, 0);
            s[kf] = acc;
        }

        // tile max per q (in-lane over 32 vals, then across l4 groups)
        float mt = -3.0e38f;
#pragma unroll
        for (int kf = 0; kf < 8; ++kf)
            mt = fmaxf(mt, fmaxf(fmaxf(s[kf][0], s[kf][1]), fmaxf(s[kf][2], s[kf][3])));
        mt = fmaxf(mt, __shfl_xor(mt, 16, 64));
        mt = fmaxf(mt, __shfl_xor(mt, 32, 64));

        float mn = fmaxf(m, mt);
        float f = __expf((m - mn) * SCALEF);
        m = mn;
        float negm = -mn * SCALEF;
        lsum *= f;
        // rescale o rows (q = l4*4 + r needs f from lane l4*4+r)
        float fr0 = __shfl(f, l4 * 4 + 0, 64);
        float fr1 = __shfl(f, l4 * 4 + 1, 64);
        float fr2 = __shfl(f, l4 * 4 + 2, 64);
        float fr3 = __shfl(f, l4 * 4 + 3, 64);
#pragma unroll
        for (int df = 0; df < 4; ++df) {
            o[df][0] *= fr0; o[df][1] *= fr1; o[df][2] *= fr2; o[df][3] *= fr3;
        }

        // w = alpha * exp(SCALE*(s - m)), accumulate l, store swizzled LDS
#pragma unroll
        for (int kf = 0; kf < 8; ++kf) {
            float2 a01 = __half22float2(*(__half2*)&areg[kf].x);
            float2 a23 = __half22float2(*(__half2*)&areg[kf].y);
            float w0 = a01.x * __expf(fmaf(s[kf][0], SCALEF, negm));
            float w1 = a01.y * __expf(fmaf(s[kf][1], SCALEF, negm));
            float w2 = a23.x * __expf(fmaf(s[kf][2], SCALEF, negm));
            float w3 = a23.y * __expf(fmaf(s[kf][3], SCALEF, negm));
            lsum += (w0 + w1) + (w2 + w3);
            u16x4 wp; wp.x = f2bf(w0); wp.y = f2bf(w1); wp.z = f2bf(w2); wp.w = f2bf(w3);
            *(u16x4*)&wlds[(l15 * 128 + kf * 16 + l4 * 4) ^ swz] = wp;
        }

        // PV over this 128-k tile
#pragma unroll
        for (int ks2 = 0; ks2 < 4; ++ks2) {
            bf16x8 wf = *(const bf16x8*)&wlds[(l15 * 128 + ks2 * 32 + l4 * 8) ^ swz];
#pragma unroll
            for (int df = 0; df < 4; ++df) {
                const u16* vb = vbase + (long)(df * 16) * 1024 + kt * 128 + ks2 * 32;
                bf16x8 vf = *(const bf16x8*)vb;
                o[df] = __builtin_amdgcn_mfma_f32_16x16x32_bf16(wf, vf, o[df], 0, 0, 0);
            }
        }
    }

    // finalize wave partial: full-row l (per q=l15)
    lsum += __shfl_xor(lsum, 16, 64);
    lsum += __shfl_xor(lsum, 32, 64);
    if (lane < 16) { cml[wave][0][l15] = m; cml[wave][1][l15] = lsum; }
#pragma unroll
    for (int df = 0; df < 4; ++df)
#pragma unroll
        for (int r = 0; r < 4; ++r)
            co[wave][l4 * 4 + r][df * 16 + l15] = o[df][r];
    __syncthreads();

    // combine 4 k-split partials; thread handles (q = tid>>4, d0 = (tid&15)*4)
    int q = tid >> 4, d0 = (tid & 15) * 4;
    float m0 = cml[0][0][q], m1 = cml[1][0][q], m2 = cml[2][0][q], m3 = cml[3][0][q];
    float ms = fmaxf(fmaxf(m0, m1), fmaxf(m2, m3));
    float c0w = __expf((m0 - ms) * SCALEF), c1w = __expf((m1 - ms) * SCALEF);
    float c2w = __expf((m2 - ms) * SCALEF), c3w = __expf((m3 - ms) * SCALEF);
    float lt = c0w * cml[0][1][q] + c1w * cml[1][1][q]
             + c2w * cml[2][1][q] + c3w * cml[3][1][q];
    f32x4 o0 = *(const f32x4*)&co[0][q][d0];
    f32x4 o1 = *(const f32x4*)&co[1][q][d0];
    f32x4 o2 = *(const f32x4*)&co[2][q][d0];
    f32x4 o3 = *(const f32x4*)&co[3][q][d0];
    float inv = __builtin_amdgcn_rcpf(lt);
    u16x4 st;
#pragma unroll
    for (int j = 0; j < 4; ++j)
        st[j] = f2bf((c0w * o0[j] + c1w * o1[j] + c2w * o2[j] + c3w * o3[j]) * inv);
    *(u16x4*)&XO[(long)(b * 512 + qg + q) * 1024 + h * 64 + d0] = st;
}

// ---------------------------------------------------------------------------
extern "C" void kernel_launch(void* const* d_in, const int* in_sizes, int n_in,
                              void* d_out, int out_size, void* d_ws, size_t ws_size,
                              hipStream_t stream)
{
    const float* q   = (const float*)d_in[0];
    const float* key = (const float*)d_in[1];
    const float* val = (const float*)d_in[2];
    const float* W   = (const float*)d_in[3];
    const float* ipb = (const float*)d_in[4];
    const float* ow  = (const float*)d_in[5];
    const float* ob  = (const float*)d_in[6];
    float* out = (float*)d_out;
    char* w = (char*)d_ws;

    // Workspace layout (bytes). Total 132,382,720 B (same as passing r3-r9).
    __half* PSIG   = (__half*)(w);                 // 64 MiB  (64,512,1024) fp16 sigmoid(phi)
    __half* ALPHAC = (__half*)(w + 67108864);      // 32 MiB  (64,256,1024) fp16 linear alpha
    float*  STATE  = (float*)(w + 100663296);      // 256 KiB (64,1024) f32
    u16*    XQAQ   = (u16*)(w + 100925440);        // 8 MiB   (2048,2048) bf16
    u16*    XK     = (u16*)(w + 109314048);        // 8 MiB   (4096,1024) bf16
    u16*    VT     = (u16*)(w + 117702656);        // 8 MiB   (64,64,1024) bf16
    u16*    XO     = (u16*)(w + 126091264);        // 4 MiB   (2048,1024) bf16
    u16*    OWBF   = (u16*)(w + 130285568);        // 2 MiB   (1024,1024) bf16
    // Overlays inside PSIG region (dead before phi GEMM writes):
    u16* QBF = (u16*)(w);                          // 4 MiB
    u16* KBF = (u16*)(w + 4194304);                // 8 MiB
    u16* VBF = (u16*)(w + 12582912);               // 8 MiB
    u16* WBF = (u16*)(w + 20971520);               // 8 MiB

    dim3 blk(256);

    // 0) f32 -> bf16 copies
    cvt_f32_bf16_k<<<dim3(2048), blk, 0, stream>>>(q, QBF, 524288);
    cvt_f32_bf16_k<<<dim3(4096), blk, 0, stream>>>(key, KBF, 1048576);
    cvt_f32_bf16_k<<<dim3(4096), blk, 0, stream>>>(val, VBF, 1048576);
    cvt_f32_bf16_k<<<dim3(4096), blk, 0, stream>>>(W, WBF, 1048576);
    cvt_f32_bf16_k<<<dim3(1024), blk, 0, stream>>>(ow, OWBF, 262144);

    // 1) XQAQ = q @ W[0:2048]^T + ipb[0:2048]  (cols 0..1023 = xqa, 1024.. = xq)
    mfma_nt<128, 128, 0><<<dim3(16, 16, 1), blk, 0, stream>>>(
        QBF, WBF, XQAQ, ipb, 1024, 1024, 1024, 2048, 0, 0, 0, 0, 0, 0, 1);
    // 2) XK = key @ W[2048:3072]^T + ipb[2048:3072]
    mfma_nt<128, 128, 0><<<dim3(8, 32, 1), blk, 0, stream>>>(
        KBF, WBF + 2097152, XK, ipb + 2048, 1024, 1024, 1024, 1024, 0, 0, 0, 0, 0, 0, 1);
    // 3) VT = transpose(val @ W[3072:4096]^T + ipb[3072:4096])
    mfma_nt<128, 128, 4><<<dim3(8, 32, 1), blk, 0, stream>>>(
        VBF, WBF + 3145728, VT, ipb + 3072, 1024, 1024, 1024, 0, 0, 0, 0, 0, 0, 0, 1);
    // 4) PSIG[n][q][k] = sigmoid(CLAMP * tanh(xqa_q . xk_k)) -> fp16
    mfma_nt<128, 128, 1><<<dim3(8, 4, 64), blk, 0, stream>>>(
        XQAQ, XK, PSIG, nullptr, 64, 2048, 1024, 1024,
        512L * 2048, 64, 1024L * 1024, 64, 8388608L, 524288L, 16);

    // 5) two 256-q chunks: DP -> fused attention (scores+softmax+PV)
    for (int c = 0; c < 2; ++c) {
        mono_dp_k<<<dim3(64), dim3(256), 0, stream>>>(PSIG, ALPHAC, STATE, c * 256);
        fused_attn_k<<<dim3(64, 16, 1), blk, 0, stream>>>(
            XQAQ, XK, VT, ALPHAC, XO, c * 256);
    }

    // 6) out = XO @ ow^T + ob  (f32)
    mfma_nt<128, 128, 3><<<dim3(8, 16, 1), blk, 0, stream>>>(
        XO, OWBF, out, ob, 1024, 1024, 1024, 1024, 0, 0, 0, 0, 0, 0, 1);
}

// Round 11
// 215.691 us; speedup vs baseline: 1.5729x; 1.3937x over previous
//
#include <hip/hip_runtime.h>
#include <hip/hip_fp16.h>
#include <hip/hip_bf16.h>
#include <math.h>

typedef unsigned short u16;
typedef __attribute__((ext_vector_type(8))) short bf16x8;
typedef __attribute__((ext_vector_type(8))) unsigned short u16x8;
typedef __attribute__((ext_vector_type(4))) unsigned short u16x4;
typedef __attribute__((ext_vector_type(4))) float f32x4;

static constexpr float CLAMPF = 3.8918202981106265f; // -log(1/0.98 - 1)
static constexpr float SCALEF = 0.125f;              // 1/sqrt(64)
static constexpr float ASCALE = 16384.f;             // 2^14 alpha storage scale

__device__ __forceinline__ u16 f2bf(float x) {
    __hip_bfloat16 h = __float2bfloat16(x);
    return *reinterpret_cast<u16*>(&h);
}

// ---------------------------------------------------------------------------
// f32 -> bf16 conversion (vectorized 4/thread)
// ---------------------------------------------------------------------------
__global__ __launch_bounds__(256)
void cvt_f32_bf16_k(const float* __restrict__ src, u16* __restrict__ dst, int n4)
{
    int i = blockIdx.x * 256 + threadIdx.x;
    if (i < n4) {
        float4 v = ((const float4*)src)[i];
        u16x4 o; o.x = f2bf(v.x); o.y = f2bf(v.y); o.z = f2bf(v.z); o.w = f2bf(v.w);
        ((u16x4*)dst)[i] = o;
    }
}

// ---------------------------------------------------------------------------
// bf16 MFMA GEMM, NT form: C[m][n] = sum_k A[m][k]*B[n][k]  (+ epilogue)
// Tile TM x TN, BK=64, 256 threads = 4 waves in 2x2 grid, mfma_f32_16x16x32_bf16.
// EPI: 0=bf16(+opt bias), 1=fp16 sigmoid(CLAMP*tanh(x)) (fast rcp), 3=f32+bias,
//      4=bf16 V-transpose store VT[((b*16+h)*64+d)*512 + k] + bias (m0 = k<512)
// TRI: phi triangular skip — tiles with k-tile > q-tile are zero-filled
//      (alpha is exactly 0 there, so phi is never consumed).
// ---------------------------------------------------------------------------
template<int TM, int TN, int EPI, bool TRI = false>
__global__ __launch_bounds__(256)
void mfma_nt(const u16* __restrict__ Ag, const u16* __restrict__ Bg,
             void* __restrict__ Cg, const float* __restrict__ bias,
             int K, int lda, int ldb, int ldc,
             long sAb, long sAh, long sBb, long sBh, long sCb, long sCh,
             int hdiv)
{
    __shared__ u16 As[TM * 64];
    __shared__ u16 Bs[TN * 64];

    int z = blockIdx.z;
    int b = z / hdiv, h = z % hdiv;
    const u16* A = Ag + (long)b * sAb + (long)h * sAh;
    const u16* B = Bg + (long)b * sBb + (long)h * sBh;

    int tid = threadIdx.x;
    int bm = blockIdx.y * TM, bn = blockIdx.x * TN;

    constexpr int AC = TM / 32;
    constexpr int BC = TN / 32;
    int srow = tid >> 3;          // 0..31
    int scol = (tid & 7) * 8;     // 0..56

    int wid = tid >> 6, lane = tid & 63;
    int wr = wid >> 1, wc = wid & 1;
    constexpr int MI = TM / 32;
    constexpr int NI = TN / 32;
    int arow0 = wr * (TM / 2) + (lane & 15);
    int bcol0 = wc * (TN / 2) + (lane & 15);
    int koff = (lane >> 4) * 8;

    if constexpr (TRI) {
        if (blockIdx.x > blockIdx.y) {   // strictly upper triangle: zero-fill
            __half* C = (__half*)Cg + (long)b * sCb + (long)h * sCh;
            int rb = bm + wr * (TM / 2) + (lane >> 4) * 4;
            int cb = bn + wc * (TN / 2) + (lane & 15);
            __half z16 = __float2half(0.f);
#pragma unroll
            for (int mi = 0; mi < MI; ++mi)
#pragma unroll
                for (int ni = 0; ni < NI; ++ni)
#pragma unroll
                    for (int r = 0; r < 4; ++r)
                        C[(long)(rb + 16 * mi + r) * ldc + cb + 16 * ni] = z16;
            return;
        }
    }

    f32x4 acc[MI][NI];
#pragma unroll
    for (int i = 0; i < MI; ++i)
#pragma unroll
        for (int j = 0; j < NI; ++j) acc[i][j] = (f32x4){0.f, 0.f, 0.f, 0.f};

    for (int kt = 0; kt < K; kt += 64) {
        u16x8 av[AC], bv[BC];
#pragma unroll
        for (int c = 0; c < AC; ++c)
            av[c] = *(const u16x8*)(A + (long)(bm + srow + 32 * c) * lda + kt + scol);
#pragma unroll
        for (int c = 0; c < BC; ++c)
            bv[c] = *(const u16x8*)(B + (long)(bn + srow + 32 * c) * ldb + kt + scol);
        __syncthreads();
#pragma unroll
        for (int c = 0; c < AC; ++c)
            *(u16x8*)&As[(srow + 32 * c) * 64 + scol] = av[c];
#pragma unroll
        for (int c = 0; c < BC; ++c)
            *(u16x8*)&Bs[(srow + 32 * c) * 64 + scol] = bv[c];
        __syncthreads();

#pragma unroll
        for (int ks = 0; ks < 2; ++ks) {
            bf16x8 af[MI], bfr[NI];
#pragma unroll
            for (int mi = 0; mi < MI; ++mi)
                af[mi] = *(const bf16x8*)&As[(arow0 + 16 * mi) * 64 + ks * 32 + koff];
#pragma unroll
            for (int ni = 0; ni < NI; ++ni)
                bfr[ni] = *(const bf16x8*)&Bs[(bcol0 + 16 * ni) * 64 + ks * 32 + koff];
#pragma unroll
            for (int mi = 0; mi < MI; ++mi)
#pragma unroll
                for (int ni = 0; ni < NI; ++ni)
                    acc[mi][ni] = __builtin_amdgcn_mfma_f32_16x16x32_bf16(
                        af[mi], bfr[ni], acc[mi][ni], 0, 0, 0);
        }
    }

    // Epilogue
    int rbase = bm + wr * (TM / 2) + (lane >> 4) * 4;
    int cbase = bn + wc * (TN / 2) + (lane & 15);
#pragma unroll
    for (int mi = 0; mi < MI; ++mi) {
#pragma unroll
        for (int ni = 0; ni < NI; ++ni) {
            int m0 = rbase + 16 * mi;
            int n = cbase + 16 * ni;
            if constexpr (EPI == 0) {
                u16* C = (u16*)Cg + (long)b * sCb + (long)h * sCh;
                float bvv = bias ? bias[n] : 0.f;
#pragma unroll
                for (int r = 0; r < 4; ++r)
                    C[(long)(m0 + r) * ldc + n] = f2bf(acc[mi][ni][r] + bvv);
            } else if constexpr (EPI == 1) {
                __half* C = (__half*)Cg + (long)b * sCb + (long)h * sCh;
#pragma unroll
                for (int r = 0; r < 4; ++r) {
                    float x = acc[mi][ni][r];
                    float e2 = __expf(2.f * x);
                    float tv = CLAMPF - (2.f * CLAMPF) * __builtin_amdgcn_rcpf(e2 + 1.f);
                    float pv = __builtin_amdgcn_rcpf(1.f + __expf(-tv));
                    C[(long)(m0 + r) * ldc + n] = __float2half(pv);
                }
            } else if constexpr (EPI == 3) {
                float* C = (float*)Cg + (long)b * sCb + (long)h * sCh;
                float bvv = bias[n];
#pragma unroll
                for (int r = 0; r < 4; ++r)
                    C[(long)(m0 + r) * ldc + n] = acc[mi][ni][r] + bvv;
            } else { // EPI == 4: VT[((b*16 + n/64)*64 + n%64)*512 + k], k = m0+r
                u16* C = (u16*)Cg;
                float bvv = bias[n];
                long vaddr = ((long)(b * 16 + (n >> 6)) * 64 + (n & 63)) * 512 + m0;
                u16x4 pk;
                pk.x = f2bf(acc[mi][ni][0] + bvv);
                pk.y = f2bf(acc[mi][ni][1] + bvv);
                pk.z = f2bf(acc[mi][ni][2] + bvv);
                pk.w = f2bf(acc[mi][ni][3] + bvv);
                *(u16x4*)(C + vaddr) = pk;
            }
        }
    }
}

// ---------------------------------------------------------------------------
// Monotonic DP, LINEAR probability domain (scaled 2^14, mass-conserving).
// TRIANGULAR: alpha[k][q] == 0 for k > q and TQ=512 < TK=1024, so only
// k < 512 ever carries mass. One WAVE per (b,h) slice (64 blocks x 64 thr);
// lane owns 8 contiguous k-rows; shift via one shfl_up. NO LDS, NO barriers,
// single dispatch for all 512 columns. Depth-8 named-register prefetch.
// c[i] = a[i]*(1-p[i]); a'[0] = fma(a0,p0,shfl_up(c7)); a'[i]=fma(a,p,c[i-1]).
// ---------------------------------------------------------------------------
#define DPL8(J) (*(const uint4*)(p + (long)min((J), 510) * 512 + k0))

#define DSTEP(PC, J) do { \
    const __half2* hp = (const __half2*)&(PC); \
    float pv[8]; \
    { float2 q01 = __half22float2(hp[0]); pv[0] = q01.x; pv[1] = q01.y; } \
    { float2 q23 = __half22float2(hp[1]); pv[2] = q23.x; pv[3] = q23.y; } \
    { float2 q45 = __half22float2(hp[2]); pv[4] = q45.x; pv[5] = q45.y; } \
    { float2 q67 = __half22float2(hp[3]); pv[6] = q67.x; pv[7] = q67.y; } \
    float c[8]; \
    _Pragma("unroll") \
    for (int r = 0; r < 8; ++r) c[r] = fmaf(-a[r], pv[r], a[r]); \
    float cp = __shfl_up(c[7], 1, 64); \
    if (lane == 0) cp = 0.f; \
    a[0] = fmaf(a[0], pv[0], cp); \
    _Pragma("unroll") \
    for (int r = 1; r < 8; ++r) a[r] = fmaf(a[r], pv[r], c[r - 1]); \
    uint4 st; \
    { __half2 h0 = __floats2half2_rn(a[0], a[1]), h1 = __floats2half2_rn(a[2], a[3]); \
      st.x = *(unsigned*)&h0; st.y = *(unsigned*)&h1; } \
    { __half2 h2 = __floats2half2_rn(a[4], a[5]), h3 = __floats2half2_rn(a[6], a[7]); \
      st.z = *(unsigned*)&h2; st.w = *(unsigned*)&h3; } \
    *(uint4*)(al + (long)(J) * 512 + k0) = st; \
} while (0)

__global__ __launch_bounds__(64)
void mono_dp_k(const __half* __restrict__ P, __half* __restrict__ AL)
{
    int n = blockIdx.x;
    int lane = threadIdx.x;                 // 0..63
    const __half* p = P + (long)n * 262144; // (512,512) sigmoid probs
    __half* al = AL + (long)n * 262144;     // (512,512) linear alpha (scaled)
    int k0 = lane * 8;

    float a[8];
#pragma unroll
    for (int r = 0; r < 8; ++r) a[r] = 0.f;
    if (lane == 0) a[0] = ASCALE;
    {   // column 0 = init distribution
        uint4 st;
        __half2 h0 = __floats2half2_rn(a[0], a[1]), h1 = __floats2half2_rn(a[2], a[3]);
        __half2 h2 = __floats2half2_rn(a[4], a[5]), h3 = __floats2half2_rn(a[6], a[7]);
        st.x = *(unsigned*)&h0; st.y = *(unsigned*)&h1;
        st.z = *(unsigned*)&h2; st.w = *(unsigned*)&h3;
        *(uint4*)(al + k0) = st;
    }

    // iteration j consumes p column j-1 (cols 0..510); depth-8 prefetch
    int j = 1;
    uint4 f0 = DPL8(0), f1 = DPL8(1), f2 = DPL8(2), f3 = DPL8(3);
    uint4 f4 = DPL8(4), f5 = DPL8(5), f6 = DPL8(6), f7 = DPL8(7);

    while (j + 7 < 512) {
        DSTEP(f0, j); f0 = DPL8(j + 7); ++j;
        DSTEP(f1, j); f1 = DPL8(j + 7); ++j;
        DSTEP(f2, j); f2 = DPL8(j + 7); ++j;
        DSTEP(f3, j); f3 = DPL8(j + 7); ++j;
        DSTEP(f4, j); f4 = DPL8(j + 7); ++j;
        DSTEP(f5, j); f5 = DPL8(j + 7); ++j;
        DSTEP(f6, j); f6 = DPL8(j + 7); ++j;
        DSTEP(f7, j); f7 = DPL8(j + 7); ++j;
    }
    while (j < 512) {
        DSTEP(f0, j);
        f0 = f1; f1 = f2; f2 = f3; f3 = f4; f4 = f5; f5 = f6; f6 = f7;
        ++j;
    }
}

// ---------------------------------------------------------------------------
// Fused attention, k < 512 only (alpha == 0 beyond), 4-way k-split of 128.
// grid (64 n, 32 q-groups); block = 4 waves; wave w handles 16 q x 128 k
// (k in [w*128,(w+1)*128)). Single k-tile per wave -> no online rescale:
// scores via MFMA (swapped: l15 = q), tile-max, w = alpha*exp(SCALE*(s-m))
// -> swizzled wave-private LDS -> PV MFMA. Wave skipped entirely if its
// k-range > qg+15 (alpha all zero there). Partials combined in LDS.
// ---------------------------------------------------------------------------
__global__ __launch_bounds__(256, 4)
void fused_attn_k(const u16* __restrict__ XQAQ, const u16* __restrict__ XK,
                  const u16* __restrict__ VT, const __half* __restrict__ AL,
                  u16* __restrict__ XO)
{
    __shared__ u16 wtile[4][2048];     // per-wave 16q x 128k bf16 (swizzled)
    __shared__ float co[4][16][64];    // per-wave partial O (q, d)
    __shared__ float cml[4][2][16];    // per-wave m, l per q

    int n = blockIdx.x; int b = n >> 4, h = n & 15;
    int tid = threadIdx.x, wave = tid >> 6, lane = tid & 63;
    int l15 = lane & 15, l4 = lane >> 4;
    int qg = blockIdx.y * 16;          // q base within 512
    u16* wlds = wtile[wave];
    int swz = (l15 & 7) << 3;

    float m = -3.0e38f, lsum = 0.f;
    f32x4 o[4];
#pragma unroll
    for (int df = 0; df < 4; ++df) o[df] = (f32x4){0.f, 0.f, 0.f, 0.f};

    if (wave * 128 < qg + 16) {        // triangular: this wave's k-range has mass
        // Q B-frags (col=q=l15)
        const u16* qbase = XQAQ + (long)(b * 512 + qg + l15) * 2048 + 1024 + h * 64 + l4 * 8;
        bf16x8 qf0 = *(const bf16x8*)(qbase);
        bf16x8 qf1 = *(const bf16x8*)(qbase + 32);

        const u16* kbase = XK + (long)(b * 512 + wave * 128 + l15) * 1024 + h * 64 + l4 * 8;
        const __half* abase = AL + (long)(n * 512 + qg + l15) * 512 + wave * 128 + l4 * 4;
        const u16* vbase = VT + (long)(n * 64 + l15) * 512 + wave * 128 + l4 * 8;

        // alpha regs (q=l15, k = wave*128 + kf*16 + l4*4 + r)
        uint2 areg[8];
#pragma unroll
        for (int kf = 0; kf < 8; ++kf)
            areg[kf] = *(const uint2*)(abase + kf * 16);

        // scores: s[kf][r] for q=l15, k = wave*128 + kf*16 + l4*4 + r
        f32x4 s[8];
#pragma unroll
        for (int kf = 0; kf < 8; ++kf) {
            const u16* kb = kbase + (long)(kf * 16) * 1024;
            bf16x8 k0 = *(const bf16x8*)kb;
            bf16x8 k1 = *(const bf16x8*)(kb + 32);
            f32x4 acc = (f32x4){0.f, 0.f, 0.f, 0.f};
            acc = __builtin_amdgcn_mfma_f32_16x16x32_bf16(k0, qf0, acc, 0, 0, 0);
            acc = __builtin_amdgcn_mfma_f32_16x16x32_bf16(k1, qf1, acc, 0, 0, 0);
            s[kf] = acc;
        }

        // tile max per q (in-lane, then across l4 groups)
        float mt = -3.0e38f;
#pragma unroll
        for (int kf = 0; kf < 8; ++kf)
            mt = fmaxf(mt, fmaxf(fmaxf(s[kf][0], s[kf][1]), fmaxf(s[kf][2], s[kf][3])));
        mt = fmaxf(mt, __shfl_xor(mt, 16, 64));
        mt = fmaxf(mt, __shfl_xor(mt, 32, 64));
        m = mt;
        float negm = -mt * SCALEF;

        // w = alpha * exp(SCALE*(s - m)), accumulate l, store swizzled LDS
#pragma unroll
        for (int kf = 0; kf < 8; ++kf) {
            float2 a01 = __half22float2(*(__half2*)&areg[kf].x);
            float2 a23 = __half22float2(*(__half2*)&areg[kf].y);
            float w0 = a01.x * __expf(fmaf(s[kf][0], SCALEF, negm));
            float w1 = a01.y * __expf(fmaf(s[kf][1], SCALEF, negm));
            float w2 = a23.x * __expf(fmaf(s[kf][2], SCALEF, negm));
            float w3 = a23.y * __expf(fmaf(s[kf][3], SCALEF, negm));
            lsum += (w0 + w1) + (w2 + w3);
            u16x4 wp; wp.x = f2bf(w0); wp.y = f2bf(w1); wp.z = f2bf(w2); wp.w = f2bf(w3);
            *(u16x4*)&wlds[(l15 * 128 + kf * 16 + l4 * 4) ^ swz] = wp;
        }

        // PV over this 128-k tile
#pragma unroll
        for (int ks2 = 0; ks2 < 4; ++ks2) {
            bf16x8 wf = *(const bf16x8*)&wlds[(l15 * 128 + ks2 * 32 + l4 * 8) ^ swz];
#pragma unroll
            for (int df = 0; df < 4; ++df) {
                const u16* vb = vbase + (long)(df * 16) * 512 + ks2 * 32;
                bf16x8 vf = *(const bf16x8*)vb;
                o[df] = __builtin_amdgcn_mfma_f32_16x16x32_bf16(wf, vf, o[df], 0, 0, 0);
            }
        }

        // full-row l per q
        lsum += __shfl_xor(lsum, 16, 64);
        lsum += __shfl_xor(lsum, 32, 64);
    }

    if (lane < 16) { cml[wave][0][l15] = m; cml[wave][1][l15] = lsum; }
#pragma unroll
    for (int df = 0; df < 4; ++df)
#pragma unroll
        for (int r = 0; r < 4; ++r)
            co[wave][l4 * 4 + r][df * 16 + l15] = o[df][r];
    __syncthreads();

    // combine 4 k-split partials; thread handles (q = tid>>4, d0 = (tid&15)*4)
    int q = tid >> 4, d0 = (tid & 15) * 4;
    float m0 = cml[0][0][q], m1 = cml[1][0][q], m2 = cml[2][0][q], m3 = cml[3][0][q];
    float ms = fmaxf(fmaxf(m0, m1), fmaxf(m2, m3));
    float c0w = __expf((m0 - ms) * SCALEF), c1w = __expf((m1 - ms) * SCALEF);
    float c2w = __expf((m2 - ms) * SCALEF), c3w = __expf((m3 - ms) * SCALEF);
    float lt = c0w * cml[0][1][q] + c1w * cml[1][1][q]
             + c2w * cml[2][1][q] + c3w * cml[3][1][q];
    f32x4 o0 = *(const f32x4*)&co[0][q][d0];
    f32x4 o1 = *(const f32x4*)&co[1][q][d0];
    f32x4 o2 = *(const f32x4*)&co[2][q][d0];
    f32x4 o3 = *(const f32x4*)&co[3][q][d0];
    float inv = __builtin_amdgcn_rcpf(lt);
    u16x4 st;
#pragma unroll
    for (int j = 0; j < 4; ++j)
        st[j] = f2bf((c0w * o0[j] + c1w * o1[j] + c2w * o2[j] + c3w * o3[j]) * inv);
    *(u16x4*)&XO[(long)(b * 512 + qg + q) * 1024 + h * 64 + d0] = st;
}

// ---------------------------------------------------------------------------
extern "C" void kernel_launch(void* const* d_in, const int* in_sizes, int n_in,
                              void* d_out, int out_size, void* d_ws, size_t ws_size,
                              hipStream_t stream)
{
    const float* q   = (const float*)d_in[0];
    const float* key = (const float*)d_in[1];
    const float* val = (const float*)d_in[2];
    const float* W   = (const float*)d_in[3];
    const float* ipb = (const float*)d_in[4];
    const float* ow  = (const float*)d_in[5];
    const float* ob  = (const float*)d_in[6];
    float* out = (float*)d_out;
    char* w = (char*)d_ws;

    // Workspace layout (bytes). Total 90,177,536 B (< prior passing 132 MB).
    __half* PSIG  = (__half*)(w);                 // 32 MiB (64,512,512) fp16 sigmoid(phi)
    __half* ALPHA = (__half*)(w + 33554432);      // 32 MiB (64,512,512) fp16 linear alpha
    u16*    XQAQ  = (u16*)(w + 67108864);         // 8 MiB  (2048,2048) bf16
    u16*    XK    = (u16*)(w + 75497472);         // 4 MiB  (4*512,1024) bf16 (k<512 only)
    u16*    VT    = (u16*)(w + 79691776);         // 4 MiB  (64,64,512) bf16
    u16*    XO    = (u16*)(w + 83886080);         // 4 MiB  (2048,1024) bf16
    u16*    OWBF  = (u16*)(w + 88080384);         // 2 MiB  (1024,1024) bf16
    // Overlays inside PSIG+ALPHA region (dead before phi GEMM writes):
    u16* QBF = (u16*)(w);                         // 4 MiB
    u16* KBF = (u16*)(w + 4194304);               // 8 MiB
    u16* VBF = (u16*)(w + 12582912);              // 8 MiB
    u16* WBF = (u16*)(w + 20971520);              // 8 MiB (ends at 28 MiB < 32)

    dim3 blk(256);

    // 0) f32 -> bf16 copies
    cvt_f32_bf16_k<<<dim3(2048), blk, 0, stream>>>(q, QBF, 524288);
    cvt_f32_bf16_k<<<dim3(4096), blk, 0, stream>>>(key, KBF, 1048576);
    cvt_f32_bf16_k<<<dim3(4096), blk, 0, stream>>>(val, VBF, 1048576);
    cvt_f32_bf16_k<<<dim3(4096), blk, 0, stream>>>(W, WBF, 1048576);
    cvt_f32_bf16_k<<<dim3(1024), blk, 0, stream>>>(ow, OWBF, 262144);

    // 1) XQAQ = q @ W[0:2048]^T + ipb[0:2048]  (cols 0..1023 = xqa, 1024.. = xq)
    mfma_nt<128, 128, 0><<<dim3(16, 16, 1), blk, 0, stream>>>(
        QBF, WBF, XQAQ, ipb, 1024, 1024, 1024, 2048, 0, 0, 0, 0, 0, 0, 1);
    // 2) XK = key[:, :512] @ Wk^T + bk   (only k<512 tokens reachable)
    mfma_nt<128, 128, 0><<<dim3(8, 4, 4), blk, 0, stream>>>(
        KBF, WBF + 2097152, XK, ipb + 2048, 1024, 1024, 1024, 1024,
        1048576L, 0, 0, 0, 524288L, 0, 1);
    // 3) VT = transpose(val[:, :512] @ Wv^T + bv): VT[(b16h)*64+d][k<512]
    mfma_nt<128, 128, 4><<<dim3(8, 4, 4), blk, 0, stream>>>(
        VBF, WBF + 3145728, VT, ipb + 3072, 1024, 1024, 1024, 0,
        1048576L, 0, 0, 0, 0, 0, 1);
    // 4) PSIG[n][q][k<512] = sigmoid(CLAMP * tanh(xqa_q . xk_k)); triangular
    mfma_nt<128, 128, 1, true><<<dim3(4, 4, 64), blk, 0, stream>>>(
        XQAQ, XK, PSIG, nullptr, 64, 2048, 1024, 512,
        1048576L, 64, 524288L, 64, 4194304L, 262144L, 16);

    // 5) monotonic DP (single dispatch, 512x512 triangular, barrier-free)
    mono_dp_k<<<dim3(64), dim3(64), 0, stream>>>(PSIG, ALPHA);

    // 6) fused attention (scores + alpha-softmax + PV), all 512 q
    fused_attn_k<<<dim3(64, 32, 1), blk, 0, stream>>>(XQAQ, XK, VT, ALPHA, XO);

    // 7) out = XO @ ow^T + ob  (f32)
    mfma_nt<128, 128, 3><<<dim3(8, 16, 1), blk, 0, stream>>>(
        XO, OWBF, out, ob, 1024, 1024, 1024, 1024, 0, 0, 0, 0, 0, 0, 1);
}

// Round 12
// 206.520 us; speedup vs baseline: 1.6428x; 1.0444x over previous
//
#include <hip/hip_runtime.h>
#include <hip/hip_fp16.h>
#include <hip/hip_bf16.h>
#include <math.h>

typedef unsigned short u16;
typedef __attribute__((ext_vector_type(8))) short bf16x8;
typedef __attribute__((ext_vector_type(8))) unsigned short u16x8;
typedef __attribute__((ext_vector_type(4))) unsigned short u16x4;
typedef __attribute__((ext_vector_type(4))) float f32x4;

static constexpr float CLAMPF = 3.8918202981106265f; // -log(1/0.98 - 1)
static constexpr float SCALEF = 0.125f;              // 1/sqrt(64)
static constexpr float ASCALE = 16384.f;             // 2^14 alpha storage scale

__device__ __forceinline__ u16 f2bf(float x) {
    __hip_bfloat16 h = __float2bfloat16(x);
    return *reinterpret_cast<u16*>(&h);
}

// ---------------------------------------------------------------------------
// Fused f32 -> bf16 conversion for all 5 inputs (one dispatch).
// Segments (in float4 units): q 524288 | key 1048576 | val 1048576 |
// W 1048576 | ow 262144.  Total 3932160 float4s.
// ---------------------------------------------------------------------------
__global__ __launch_bounds__(256)
void cvt_all_k(const float* __restrict__ q, const float* __restrict__ key,
               const float* __restrict__ val, const float* __restrict__ W,
               const float* __restrict__ ow,
               u16* __restrict__ QBF, u16* __restrict__ KBF,
               u16* __restrict__ VBF, u16* __restrict__ WBF,
               u16* __restrict__ OWBF)
{
    long i = (long)blockIdx.x * 256 + threadIdx.x;
    const float* src; u16* dst; long off;
    if (i < 524288)       { src = q;   dst = QBF;  off = i; }
    else if (i < 1572864) { src = key; dst = KBF;  off = i - 524288; }
    else if (i < 2621440) { src = val; dst = VBF;  off = i - 1572864; }
    else if (i < 3670016) { src = W;   dst = WBF;  off = i - 2621440; }
    else if (i < 3932160) { src = ow;  dst = OWBF; off = i - 3670016; }
    else return;
    float4 v = ((const float4*)src)[off];
    u16x4 o; o.x = f2bf(v.x); o.y = f2bf(v.y); o.z = f2bf(v.z); o.w = f2bf(v.w);
    ((u16x4*)dst)[off] = o;
}

// ---------------------------------------------------------------------------
// bf16 MFMA GEMM, NT form: C[m][n] = sum_k A[m][k]*B[n][k]  (+ epilogue)
// Tile TM x TN, BK=64, 256 threads = 4 waves in 2x2 grid, mfma_f32_16x16x32_bf16.
// EPI: 0=bf16(+opt bias), 1=fp16 sigmoid(CLAMP*tanh(x)) (fast rcp), 3=f32+bias,
//      4=bf16 V-transpose store VT[((b*16+h)*64+d)*512 + k] + bias (m0 = k<512)
// TRI: phi triangular skip — tiles with k-tile > q-tile are zero-filled
//      (alpha is exactly 0 there, so phi is never consumed).
// ---------------------------------------------------------------------------
template<int TM, int TN, int EPI, bool TRI = false>
__global__ __launch_bounds__(256)
void mfma_nt(const u16* __restrict__ Ag, const u16* __restrict__ Bg,
             void* __restrict__ Cg, const float* __restrict__ bias,
             int K, int lda, int ldb, int ldc,
             long sAb, long sAh, long sBb, long sBh, long sCb, long sCh,
             int hdiv)
{
    __shared__ u16 As[TM * 64];
    __shared__ u16 Bs[TN * 64];

    int z = blockIdx.z;
    int b = z / hdiv, h = z % hdiv;
    const u16* A = Ag + (long)b * sAb + (long)h * sAh;
    const u16* B = Bg + (long)b * sBb + (long)h * sBh;

    int tid = threadIdx.x;
    int bm = blockIdx.y * TM, bn = blockIdx.x * TN;

    constexpr int AC = TM / 32;
    constexpr int BC = TN / 32;
    int srow = tid >> 3;          // 0..31
    int scol = (tid & 7) * 8;     // 0..56

    int wid = tid >> 6, lane = tid & 63;
    int wr = wid >> 1, wc = wid & 1;
    constexpr int MI = TM / 32;
    constexpr int NI = TN / 32;
    int arow0 = wr * (TM / 2) + (lane & 15);
    int bcol0 = wc * (TN / 2) + (lane & 15);
    int koff = (lane >> 4) * 8;

    if constexpr (TRI) {
        if (blockIdx.x > blockIdx.y) {   // strictly upper triangle: zero-fill
            __half* C = (__half*)Cg + (long)b * sCb + (long)h * sCh;
            int rb = bm + wr * (TM / 2) + (lane >> 4) * 4;
            int cb = bn + wc * (TN / 2) + (lane & 15);
            __half z16 = __float2half(0.f);
#pragma unroll
            for (int mi = 0; mi < MI; ++mi)
#pragma unroll
                for (int ni = 0; ni < NI; ++ni)
#pragma unroll
                    for (int r = 0; r < 4; ++r)
                        C[(long)(rb + 16 * mi + r) * ldc + cb + 16 * ni] = z16;
            return;
        }
    }

    f32x4 acc[MI][NI];
#pragma unroll
    for (int i = 0; i < MI; ++i)
#pragma unroll
        for (int j = 0; j < NI; ++j) acc[i][j] = (f32x4){0.f, 0.f, 0.f, 0.f};

    for (int kt = 0; kt < K; kt += 64) {
        u16x8 av[AC], bv[BC];
#pragma unroll
        for (int c = 0; c < AC; ++c)
            av[c] = *(const u16x8*)(A + (long)(bm + srow + 32 * c) * lda + kt + scol);
#pragma unroll
        for (int c = 0; c < BC; ++c)
            bv[c] = *(const u16x8*)(B + (long)(bn + srow + 32 * c) * ldb + kt + scol);
        __syncthreads();
#pragma unroll
        for (int c = 0; c < AC; ++c)
            *(u16x8*)&As[(srow + 32 * c) * 64 + scol] = av[c];
#pragma unroll
        for (int c = 0; c < BC; ++c)
            *(u16x8*)&Bs[(srow + 32 * c) * 64 + scol] = bv[c];
        __syncthreads();

#pragma unroll
        for (int ks = 0; ks < 2; ++ks) {
            bf16x8 af[MI], bfr[NI];
#pragma unroll
            for (int mi = 0; mi < MI; ++mi)
                af[mi] = *(const bf16x8*)&As[(arow0 + 16 * mi) * 64 + ks * 32 + koff];
#pragma unroll
            for (int ni = 0; ni < NI; ++ni)
                bfr[ni] = *(const bf16x8*)&Bs[(bcol0 + 16 * ni) * 64 + ks * 32 + koff];
#pragma unroll
            for (int mi = 0; mi < MI; ++mi)
#pragma unroll
                for (int ni = 0; ni < NI; ++ni)
                    acc[mi][ni] = __builtin_amdgcn_mfma_f32_16x16x32_bf16(
                        af[mi], bfr[ni], acc[mi][ni], 0, 0, 0);
        }
    }

    // Epilogue
    int rbase = bm + wr * (TM / 2) + (lane >> 4) * 4;
    int cbase = bn + wc * (TN / 2) + (lane & 15);
#pragma unroll
    for (int mi = 0; mi < MI; ++mi) {
#pragma unroll
        for (int ni = 0; ni < NI; ++ni) {
            int m0 = rbase + 16 * mi;
            int n = cbase + 16 * ni;
            if constexpr (EPI == 0) {
                u16* C = (u16*)Cg + (long)b * sCb + (long)h * sCh;
                float bvv = bias ? bias[n] : 0.f;
#pragma unroll
                for (int r = 0; r < 4; ++r)
                    C[(long)(m0 + r) * ldc + n] = f2bf(acc[mi][ni][r] + bvv);
            } else if constexpr (EPI == 1) {
                __half* C = (__half*)Cg + (long)b * sCb + (long)h * sCh;
#pragma unroll
                for (int r = 0; r < 4; ++r) {
                    float x = acc[mi][ni][r];
                    float e2 = __expf(2.f * x);
                    float tv = CLAMPF - (2.f * CLAMPF) * __builtin_amdgcn_rcpf(e2 + 1.f);
                    float pv = __builtin_amdgcn_rcpf(1.f + __expf(-tv));
                    C[(long)(m0 + r) * ldc + n] = __float2half(pv);
                }
            } else if constexpr (EPI == 3) {
                float* C = (float*)Cg + (long)b * sCb + (long)h * sCh;
                float bvv = bias[n];
#pragma unroll
                for (int r = 0; r < 4; ++r)
                    C[(long)(m0 + r) * ldc + n] = acc[mi][ni][r] + bvv;
            } else { // EPI == 4: VT[((b*16 + n/64)*64 + n%64)*512 + k], k = m0+r
                u16* C = (u16*)Cg;
                float bvv = bias[n];
                long vaddr = ((long)(b * 16 + (n >> 6)) * 64 + (n & 63)) * 512 + m0;
                u16x4 pk;
                pk.x = f2bf(acc[mi][ni][0] + bvv);
                pk.y = f2bf(acc[mi][ni][1] + bvv);
                pk.z = f2bf(acc[mi][ni][2] + bvv);
                pk.w = f2bf(acc[mi][ni][3] + bvv);
                *(u16x4*)(C + vaddr) = pk;
            }
        }
    }
}

// ---------------------------------------------------------------------------
// Monotonic DP, LINEAR probability domain (scaled 2^14, mass-conserving).
// TRIANGULAR 512x512. One WAVE per (b,h) slice; lane owns 8 contiguous
// k-rows; shift via one shfl_up. NO LDS, NO barriers. Depth-16 prefetch
// (covers ~900cy HBM latency at ~56cy/col). Step reordered so the shfl
// issues early (c7 first) and a[0] lands last — same ops, same rounding.
// c[i] = a[i]*(1-p[i]); a'[0] = fma(a0,p0,shfl_up(c7)); a'[i]=fma(a,p,c[i-1]).
// ---------------------------------------------------------------------------
#define DPL8(J) (*(const uint4*)(p + (long)min((J), 510) * 512 + k0))

#define DSTEP(PC, J) do { \
    const __half2* hp = (const __half2*)&(PC); \
    float p6, p7; \
    { float2 q67 = __half22float2(hp[3]); p6 = q67.x; p7 = q67.y; } \
    float c7 = fmaf(-a[7], p7, a[7]); \
    float cp = __shfl_up(c7, 1, 64); \
    float pv[6]; \
    { float2 q01 = __half22float2(hp[0]); pv[0] = q01.x; pv[1] = q01.y; } \
    { float2 q23 = __half22float2(hp[1]); pv[2] = q23.x; pv[3] = q23.y; } \
    { float2 q45 = __half22float2(hp[2]); pv[4] = q45.x; pv[5] = q45.y; } \
    float c[7]; \
    _Pragma("unroll") \
    for (int r = 0; r < 6; ++r) c[r] = fmaf(-a[r], pv[r], a[r]); \
    c[6] = fmaf(-a[6], p6, a[6]); \
    a[7] = fmaf(a[7], p7, c[6]); \
    _Pragma("unroll") \
    for (int r = 1; r < 6; ++r) a[r] = fmaf(a[r], pv[r], c[r - 1]); \
    a[6] = fmaf(a[6], p6, c[5]); \
    if (lane == 0) cp = 0.f; \
    a[0] = fmaf(a[0], pv[0], cp); \
    uint4 st; \
    { __half2 h0 = __floats2half2_rn(a[0], a[1]), h1 = __floats2half2_rn(a[2], a[3]); \
      st.x = *(unsigned*)&h0; st.y = *(unsigned*)&h1; } \
    { __half2 h2 = __floats2half2_rn(a[4], a[5]), h3 = __floats2half2_rn(a[6], a[7]); \
      st.z = *(unsigned*)&h2; st.w = *(unsigned*)&h3; } \
    *(uint4*)(al + (long)(J) * 512 + k0) = st; \
} while (0)

__global__ __launch_bounds__(64)
void mono_dp_k(const __half* __restrict__ P, __half* __restrict__ AL)
{
    int n = blockIdx.x;
    int lane = threadIdx.x;                 // 0..63
    const __half* p = P + (long)n * 262144; // (512,512) sigmoid probs
    __half* al = AL + (long)n * 262144;     // (512,512) linear alpha (scaled)
    int k0 = lane * 8;

    float a[8];
#pragma unroll
    for (int r = 0; r < 8; ++r) a[r] = 0.f;
    if (lane == 0) a[0] = ASCALE;
    {   // column 0 = init distribution
        uint4 st;
        __half2 h0 = __floats2half2_rn(a[0], a[1]), h1 = __floats2half2_rn(a[2], a[3]);
        __half2 h2 = __floats2half2_rn(a[4], a[5]), h3 = __floats2half2_rn(a[6], a[7]);
        st.x = *(unsigned*)&h0; st.y = *(unsigned*)&h1;
        st.z = *(unsigned*)&h2; st.w = *(unsigned*)&h3;
        *(uint4*)(al + k0) = st;
    }

    // iteration j consumes p column j-1 (cols 0..510); depth-16 prefetch
    int j = 1;
    uint4 f0 = DPL8(0),  f1 = DPL8(1),  f2 = DPL8(2),  f3 = DPL8(3);
    uint4 f4 = DPL8(4),  f5 = DPL8(5),  f6 = DPL8(6),  f7 = DPL8(7);
    uint4 f8 = DPL8(8),  f9 = DPL8(9),  fA = DPL8(10), fB = DPL8(11);
    uint4 fC = DPL8(12), fD = DPL8(13), fE = DPL8(14), fF = DPL8(15);

    while (j + 15 < 512) {
        DSTEP(f0, j); f0 = DPL8(j + 15); ++j;
        DSTEP(f1, j); f1 = DPL8(j + 15); ++j;
        DSTEP(f2, j); f2 = DPL8(j + 15); ++j;
        DSTEP(f3, j); f3 = DPL8(j + 15); ++j;
        DSTEP(f4, j); f4 = DPL8(j + 15); ++j;
        DSTEP(f5, j); f5 = DPL8(j + 15); ++j;
        DSTEP(f6, j); f6 = DPL8(j + 15); ++j;
        DSTEP(f7, j); f7 = DPL8(j + 15); ++j;
        DSTEP(f8, j); f8 = DPL8(j + 15); ++j;
        DSTEP(f9, j); f9 = DPL8(j + 15); ++j;
        DSTEP(fA, j); fA = DPL8(j + 15); ++j;
        DSTEP(fB, j); fB = DPL8(j + 15); ++j;
        DSTEP(fC, j); fC = DPL8(j + 15); ++j;
        DSTEP(fD, j); fD = DPL8(j + 15); ++j;
        DSTEP(fE, j); fE = DPL8(j + 15); ++j;
        DSTEP(fF, j); fF = DPL8(j + 15); ++j;
    }
    while (j < 512) {
        DSTEP(f0, j);
        f0 = f1; f1 = f2; f2 = f3; f3 = f4; f4 = f5; f5 = f6; f6 = f7;
        f7 = f8; f8 = f9; f9 = fA; fA = fB; fB = fC; fC = fD; fD = fE; fE = fF;
        ++j;
    }
}

// ---------------------------------------------------------------------------
// Fused attention, k < 512 only (alpha == 0 beyond), 4-way k-split of 128.
// grid (64 n, 32 q-groups); block = 4 waves; wave w handles 16 q x 128 k
// (k in [w*128,(w+1)*128)). Single k-tile per wave -> no online rescale:
// scores via MFMA (swapped: l15 = q), tile-max, w = alpha*exp(SCALE*(s-m))
// -> swizzled wave-private LDS -> PV MFMA. Wave skipped entirely if its
// k-range > qg+15 (alpha all zero there). Partials combined in LDS.
// ---------------------------------------------------------------------------
__global__ __launch_bounds__(256, 4)
void fused_attn_k(const u16* __restrict__ XQAQ, const u16* __restrict__ XK,
                  const u16* __restrict__ VT, const __half* __restrict__ AL,
                  u16* __restrict__ XO)
{
    __shared__ u16 wtile[4][2048];     // per-wave 16q x 128k bf16 (swizzled)
    __shared__ float co[4][16][64];    // per-wave partial O (q, d)
    __shared__ float cml[4][2][16];    // per-wave m, l per q

    int n = blockIdx.x; int b = n >> 4, h = n & 15;
    int tid = threadIdx.x, wave = tid >> 6, lane = tid & 63;
    int l15 = lane & 15, l4 = lane >> 4;
    int qg = blockIdx.y * 16;          // q base within 512
    u16* wlds = wtile[wave];
    int swz = (l15 & 7) << 3;

    float m = -3.0e38f, lsum = 0.f;
    f32x4 o[4];
#pragma unroll
    for (int df = 0; df < 4; ++df) o[df] = (f32x4){0.f, 0.f, 0.f, 0.f};

    if (wave * 128 < qg + 16) {        // triangular: this wave's k-range has mass
        // Q B-frags (col=q=l15)
        const u16* qbase = XQAQ + (long)(b * 512 + qg + l15) * 2048 + 1024 + h * 64 + l4 * 8;
        bf16x8 qf0 = *(const bf16x8*)(qbase);
        bf16x8 qf1 = *(const bf16x8*)(qbase + 32);

        const u16* kbase = XK + (long)(b * 512 + wave * 128 + l15) * 1024 + h * 64 + l4 * 8;
        const __half* abase = AL + (long)(n * 512 + qg + l15) * 512 + wave * 128 + l4 * 4;
        const u16* vbase = VT + (long)(n * 64 + l15) * 512 + wave * 128 + l4 * 8;

        // alpha regs (q=l15, k = wave*128 + kf*16 + l4*4 + r)
        uint2 areg[8];
#pragma unroll
        for (int kf = 0; kf < 8; ++kf)
            areg[kf] = *(const uint2*)(abase + kf * 16);

        // scores: s[kf][r] for q=l15, k = wave*128 + kf*16 + l4*4 + r
        f32x4 s[8];
#pragma unroll
        for (int kf = 0; kf < 8; ++kf) {
            const u16* kb = kbase + (long)(kf * 16) * 1024;
            bf16x8 k0 = *(const bf16x8*)kb;
            bf16x8 k1 = *(const bf16x8*)(kb + 32);
            f32x4 acc = (f32x4){0.f, 0.f, 0.f, 0.f};
            acc = __builtin_amdgcn_mfma_f32_16x16x32_bf16(k0, qf0, acc, 0, 0, 0);
            acc = __builtin_amdgcn_mfma_f32_16x16x32_bf16(k1, qf1, acc, 0, 0, 0);
            s[kf] = acc;
        }

        // tile max per q (in-lane, then across l4 groups)
        float mt = -3.0e38f;
#pragma unroll
        for (int kf = 0; kf < 8; ++kf)
            mt = fmaxf(mt, fmaxf(fmaxf(s[kf][0], s[kf][1]), fmaxf(s[kf][2], s[kf][3])));
        mt = fmaxf(mt, __shfl_xor(mt, 16, 64));
        mt = fmaxf(mt, __shfl_xor(mt, 32, 64));
        m = mt;
        float negm = -mt * SCALEF;

        // w = alpha * exp(SCALE*(s - m)), accumulate l, store swizzled LDS
#pragma unroll
        for (int kf = 0; kf < 8; ++kf) {
            float2 a01 = __half22float2(*(__half2*)&areg[kf].x);
            float2 a23 = __half22float2(*(__half2*)&areg[kf].y);
            float w0 = a01.x * __expf(fmaf(s[kf][0], SCALEF, negm));
            float w1 = a01.y * __expf(fmaf(s[kf][1], SCALEF, negm));
            float w2 = a23.x * __expf(fmaf(s[kf][2], SCALEF, negm));
            float w3 = a23.y * __expf(fmaf(s[kf][3], SCALEF, negm));
            lsum += (w0 + w1) + (w2 + w3);
            u16x4 wp; wp.x = f2bf(w0); wp.y = f2bf(w1); wp.z = f2bf(w2); wp.w = f2bf(w3);
            *(u16x4*)&wlds[(l15 * 128 + kf * 16 + l4 * 4) ^ swz] = wp;
        }

        // PV over this 128-k tile
#pragma unroll
        for (int ks2 = 0; ks2 < 4; ++ks2) {
            bf16x8 wf = *(const bf16x8*)&wlds[(l15 * 128 + ks2 * 32 + l4 * 8) ^ swz];
#pragma unroll
            for (int df = 0; df < 4; ++df) {
                const u16* vb = vbase + (long)(df * 16) * 512 + ks2 * 32;
                bf16x8 vf = *(const bf16x8*)vb;
                o[df] = __builtin_amdgcn_mfma_f32_16x16x32_bf16(wf, vf, o[df], 0, 0, 0);
            }
        }

        // full-row l per q
        lsum += __shfl_xor(lsum, 16, 64);
        lsum += __shfl_xor(lsum, 32, 64);
    }

    if (lane < 16) { cml[wave][0][l15] = m; cml[wave][1][l15] = lsum; }
#pragma unroll
    for (int df = 0; df < 4; ++df)
#pragma unroll
        for (int r = 0; r < 4; ++r)
            co[wave][l4 * 4 + r][df * 16 + l15] = o[df][r];
    __syncthreads();

    // combine 4 k-split partials; thread handles (q = tid>>4, d0 = (tid&15)*4)
    int q = tid >> 4, d0 = (tid & 15) * 4;
    float m0 = cml[0][0][q], m1 = cml[1][0][q], m2 = cml[2][0][q], m3 = cml[3][0][q];
    float ms = fmaxf(fmaxf(m0, m1), fmaxf(m2, m3));
    float c0w = __expf((m0 - ms) * SCALEF), c1w = __expf((m1 - ms) * SCALEF);
    float c2w = __expf((m2 - ms) * SCALEF), c3w = __expf((m3 - ms) * SCALEF);
    float lt = c0w * cml[0][1][q] + c1w * cml[1][1][q]
             + c2w * cml[2][1][q] + c3w * cml[3][1][q];
    f32x4 o0 = *(const f32x4*)&co[0][q][d0];
    f32x4 o1 = *(const f32x4*)&co[1][q][d0];
    f32x4 o2 = *(const f32x4*)&co[2][q][d0];
    f32x4 o3 = *(const f32x4*)&co[3][q][d0];
    float inv = __builtin_amdgcn_rcpf(lt);
    u16x4 st;
#pragma unroll
    for (int j = 0; j < 4; ++j)
        st[j] = f2bf((c0w * o0[j] + c1w * o1[j] + c2w * o2[j] + c3w * o3[j]) * inv);
    *(u16x4*)&XO[(long)(b * 512 + qg + q) * 1024 + h * 64 + d0] = st;
}

// ---------------------------------------------------------------------------
extern "C" void kernel_launch(void* const* d_in, const int* in_sizes, int n_in,
                              void* d_out, int out_size, void* d_ws, size_t ws_size,
                              hipStream_t stream)
{
    const float* q   = (const float*)d_in[0];
    const float* key = (const float*)d_in[1];
    const float* val = (const float*)d_in[2];
    const float* W   = (const float*)d_in[3];
    const float* ipb = (const float*)d_in[4];
    const float* ow  = (const float*)d_in[5];
    const float* ob  = (const float*)d_in[6];
    float* out = (float*)d_out;
    char* w = (char*)d_ws;

    // Workspace layout (bytes). Total 90,177,536 B (same as passing r11).
    __half* PSIG  = (__half*)(w);                 // 32 MiB (64,512,512) fp16 sigmoid(phi)
    __half* ALPHA = (__half*)(w + 33554432);      // 32 MiB (64,512,512) fp16 linear alpha
    u16*    XQAQ  = (u16*)(w + 67108864);         // 8 MiB  (2048,2048) bf16
    u16*    XK    = (u16*)(w + 75497472);         // 4 MiB  (4*512,1024) bf16 (k<512 only)
    u16*    VT    = (u16*)(w + 79691776);         // 4 MiB  (64,64,512) bf16
    u16*    XO    = (u16*)(w + 83886080);         // 4 MiB  (2048,1024) bf16
    u16*    OWBF  = (u16*)(w + 88080384);         // 2 MiB  (1024,1024) bf16
    // Overlays inside PSIG+ALPHA region (dead before phi GEMM writes):
    u16* QBF = (u16*)(w);                         // 4 MiB
    u16* KBF = (u16*)(w + 4194304);               // 8 MiB
    u16* VBF = (u16*)(w + 12582912);              // 8 MiB
    u16* WBF = (u16*)(w + 20971520);              // 8 MiB (ends at 28 MiB < 32)

    dim3 blk(256);

    // 0) f32 -> bf16 copies (single fused dispatch)
    cvt_all_k<<<dim3(15360), blk, 0, stream>>>(
        q, key, val, W, ow, QBF, KBF, VBF, WBF, OWBF);

    // 1) XQAQ = q @ W[0:2048]^T + ipb[0:2048]  (cols 0..1023 = xqa, 1024.. = xq)
    mfma_nt<128, 128, 0><<<dim3(16, 16, 1), blk, 0, stream>>>(
        QBF, WBF, XQAQ, ipb, 1024, 1024, 1024, 2048, 0, 0, 0, 0, 0, 0, 1);
    // 2) XK = key[:, :512] @ Wk^T + bk   (only k<512 tokens reachable)
    mfma_nt<128, 128, 0><<<dim3(8, 4, 4), blk, 0, stream>>>(
        KBF, WBF + 2097152, XK, ipb + 2048, 1024, 1024, 1024, 1024,
        1048576L, 0, 0, 0, 524288L, 0, 1);
    // 3) VT = transpose(val[:, :512] @ Wv^T + bv): VT[(b16h)*64+d][k<512]
    mfma_nt<128, 128, 4><<<dim3(8, 4, 4), blk, 0, stream>>>(
        VBF, WBF + 3145728, VT, ipb + 3072, 1024, 1024, 1024, 0,
        1048576L, 0, 0, 0, 0, 0, 1);
    // 4) PSIG[n][q][k<512] = sigmoid(CLAMP * tanh(xqa_q . xk_k)); triangular
    mfma_nt<128, 128, 1, true><<<dim3(4, 4, 64), blk, 0, stream>>>(
        XQAQ, XK, PSIG, nullptr, 64, 2048, 1024, 512,
        1048576L, 64, 524288L, 64, 4194304L, 262144L, 16);

    // 5) monotonic DP (single dispatch, 512x512 triangular, barrier-free)
    mono_dp_k<<<dim3(64), dim3(64), 0, stream>>>(PSIG, ALPHA);

    // 6) fused attention (scores + alpha-softmax + PV), all 512 q
    fused_attn_k<<<dim3(64, 32, 1), blk, 0, stream>>>(XQAQ, XK, VT, ALPHA, XO);

    // 7) out = XO @ ow^T + ob  (f32)
    mfma_nt<128, 128, 3><<<dim3(8, 16, 1), blk, 0, stream>>>(
        XO, OWBF, out, ob, 1024, 1024, 1024, 1024, 0, 0, 0, 0, 0, 0, 1);
}